// Round 1
// baseline (350.329 us; speedup 1.0000x reference)
//
#include <hip/hip_runtime.h>

// ---------------------------------------------------------------------------
// Fused MHA block for MI355X (gfx950).
// B=2, S=2048, E=1024, H=16, D=64. f32 in/out, bf16 MFMA internally.
//
// Pipeline:
//   cvt:   x,Wq,Wk,Wv,Wo  f32 -> bf16 (ws)
//   gemm<0>: Q = x@Wq^T+bq  -> bf16 [B,H,S,D]
//   gemm<0>: K = x@Wk^T+bk  -> bf16 [B,H,S,D]
//   gemm<1>: V = x@Wv^T+bv  -> bf16 [B,H,D,S]   (transposed for PV B-operand)
//   attn:   flash attention -> ctx bf16 [B,S,E]
//   gemm<2>: out = ctx@Wo^T+bo -> f32 d_out
//
// Workspace: 48 MB (ctx aliases xb; xb dead after V projection).
// ---------------------------------------------------------------------------

using u16 = unsigned short;
using u32 = unsigned int;

typedef __bf16 bf16x8 __attribute__((ext_vector_type(8)));
typedef float  f32x4  __attribute__((ext_vector_type(4)));

constexpr int GB = 2;
constexpr int GS = 2048;
constexpr int GH = 16;
constexpr int GD = 64;
constexpr int GE = 1024;
constexpr int GM = GB * GS;   // 4096 rows

__device__ __forceinline__ u16 f2bf(float f) {
    u32 u = __float_as_uint(f);
    u += 0x7FFFu + ((u >> 16) & 1u);   // RTNE
    return (u16)(u >> 16);
}

// ---------------------------------------------------------------- cvt kernel
__global__ void cvt_kernel(const float* __restrict__ in, u16* __restrict__ out, int n) {
    int idx = blockIdx.x * blockDim.x + threadIdx.x;
    int stride = gridDim.x * blockDim.x;
    for (int i = idx * 4; i < n; i += stride * 4) {
        float4 f = *reinterpret_cast<const float4*>(in + i);
        ushort4 o;
        o.x = f2bf(f.x); o.y = f2bf(f.y); o.z = f2bf(f.z); o.w = f2bf(f.w);
        *reinterpret_cast<ushort4*>(out + i) = o;
    }
}

// ---------------------------------------------------------------- GEMM
// C[m,n] = sum_k A[m,k]*W[n,k] + bias[n].  A: [4096,1024] bf16 row-major,
// W: [1024,1024] bf16 row-major (Linear weight, rows = out features).
// MODE 0: bf16 out at [B,H,S,D]; MODE 1: bf16 out at [B,H,D,S]; MODE 2: f32 out [m,n].
template <int MODE>
__global__ __launch_bounds__(256)
void gemm_bt(const u16* __restrict__ A, const u16* __restrict__ Bw,
             const float* __restrict__ bias, void* __restrict__ outp) {
    constexpr int Kd = GE, Nd = GE;
    constexpr int BM = 128, BN = 128, BK = 32, LDP = 40;  // pad 32->40 bf16
    __shared__ u16 As[BM * LDP];
    __shared__ u16 Bs[BN * LDP];

    const int tid = threadIdx.x;
    const int m0 = blockIdx.y * BM;
    const int n0 = blockIdx.x * BN;
    const int wave = tid >> 6, lane = tid & 63;
    const int wm = (wave >> 1) * 64, wn = (wave & 1) * 64;
    const int g = lane >> 4, rw = lane & 15;

    f32x4 acc[4][4] = {};

    for (int kt = 0; kt < Kd; kt += BK) {
        __syncthreads();
#pragma unroll
        for (int it = 0; it < 2; ++it) {
            int c = tid + it * 256;            // 512 chunks of 8 bf16
            int row = c >> 2, kh = c & 3;
            *reinterpret_cast<uint4*>(&As[row * LDP + kh * 8]) =
                *reinterpret_cast<const uint4*>(&A[(size_t)(m0 + row) * Kd + kt + kh * 8]);
            *reinterpret_cast<uint4*>(&Bs[row * LDP + kh * 8]) =
                *reinterpret_cast<const uint4*>(&Bw[(size_t)(n0 + row) * Kd + kt + kh * 8]);
        }
        __syncthreads();

        bf16x8 aF[4], bF[4];
#pragma unroll
        for (int mf = 0; mf < 4; ++mf)
            aF[mf] = *reinterpret_cast<const bf16x8*>(&As[(wm + mf * 16 + rw) * LDP + g * 8]);
#pragma unroll
        for (int nf = 0; nf < 4; ++nf)
            bF[nf] = *reinterpret_cast<const bf16x8*>(&Bs[(wn + nf * 16 + rw) * LDP + g * 8]);
#pragma unroll
        for (int mf = 0; mf < 4; ++mf)
#pragma unroll
            for (int nf = 0; nf < 4; ++nf)
                acc[mf][nf] = __builtin_amdgcn_mfma_f32_16x16x32_bf16(aF[mf], bF[nf], acc[mf][nf], 0, 0, 0);
    }

#pragma unroll
    for (int mf = 0; mf < 4; ++mf)
#pragma unroll
        for (int nf = 0; nf < 4; ++nf)
#pragma unroll
            for (int r = 0; r < 4; ++r) {
                int m = m0 + wm + mf * 16 + g * 4 + r;
                int n = n0 + wn + nf * 16 + rw;
                float v = acc[mf][nf][r] + bias[n];
                if constexpr (MODE == 2) {
                    reinterpret_cast<float*>(outp)[(size_t)m * Nd + n] = v;
                } else {
                    u16 hv = f2bf(v);
                    int b = m >> 11, s = m & (GS - 1);
                    int h = n >> 6, d = n & 63;
                    if constexpr (MODE == 0)
                        reinterpret_cast<u16*>(outp)[(((size_t)(b * GH + h)) * GS + s) * GD + d] = hv;
                    else
                        reinterpret_cast<u16*>(outp)[(((size_t)(b * GH + h)) * GD + d) * GS + s] = hv;
                }
            }
}

// ---------------------------------------------------------------- attention
// Flash attention. Grid (S/64, B*H), 256 threads = 4 waves, each wave owns 16
// q-rows. KV tile 64. Q,K: [B,H,S,D]; V: [B,H,D,S] (pre-transposed).
__global__ __launch_bounds__(256)
void attn_kernel(const u16* __restrict__ Q, const u16* __restrict__ Kp,
                 const u16* __restrict__ VT, u16* __restrict__ ctx) {
    const int bh = blockIdx.y;
    const int qb = blockIdx.x * 64;
    const int wave = threadIdx.x >> 6, lane = threadIdx.x & 63;
    const int g = lane >> 4, rw = lane & 15;
    const int q0 = qb + wave * 16;

    const u16* Qbh = Q  + (size_t)bh * GS * GD;
    const u16* Kbh = Kp + (size_t)bh * GS * GD;
    const u16* Vbh = VT + (size_t)bh * GD * GS;

    __shared__ u16 pLds[2][4][16][72];   // double-buffered per-wave P tiles

    bf16x8 qf0 = *reinterpret_cast<const bf16x8*>(&Qbh[(size_t)(q0 + rw) * GD + g * 8]);
    bf16x8 qf1 = *reinterpret_cast<const bf16x8*>(&Qbh[(size_t)(q0 + rw) * GD + 32 + g * 8]);

    f32x4 O[4] = {};
    float mrow[4] = {-1e30f, -1e30f, -1e30f, -1e30f};
    float lrow[4] = {};

    const float SC = 0.125f * 1.44269504088896f;   // scale * log2(e)

    for (int kv0 = 0; kv0 < GS; kv0 += 64) {
        // ---- QK^T: scores for 16 q x 64 kv
        f32x4 sc[4];
#pragma unroll
        for (int nf = 0; nf < 4; ++nf) {
            bf16x8 k0 = *reinterpret_cast<const bf16x8*>(&Kbh[(size_t)(kv0 + nf * 16 + rw) * GD + g * 8]);
            bf16x8 k1 = *reinterpret_cast<const bf16x8*>(&Kbh[(size_t)(kv0 + nf * 16 + rw) * GD + 32 + g * 8]);
            f32x4 z = {0.f, 0.f, 0.f, 0.f};
            z = __builtin_amdgcn_mfma_f32_16x16x32_bf16(qf0, k0, z, 0, 0, 0);
            sc[nf] = __builtin_amdgcn_mfma_f32_16x16x32_bf16(qf1, k1, z, 0, 0, 0);
        }
        // ---- online softmax (log2 domain)
        float rowmax[4];
#pragma unroll
        for (int r = 0; r < 4; ++r) {
            float mx = fmaxf(fmaxf(sc[0][r], sc[1][r]), fmaxf(sc[2][r], sc[3][r]));
#pragma unroll
            for (int off = 1; off < 16; off <<= 1)
                mx = fmaxf(mx, __shfl_xor(mx, off, 64));
            rowmax[r] = mx * SC;
        }
        float alpha[4];
#pragma unroll
        for (int r = 0; r < 4; ++r) {
            float mn = fmaxf(mrow[r], rowmax[r]);
            alpha[r] = exp2f(mrow[r] - mn);
            mrow[r] = mn;
        }
        float rs[4] = {};
        u16 pb[4][4];
#pragma unroll
        for (int nf = 0; nf < 4; ++nf)
#pragma unroll
            for (int r = 0; r < 4; ++r) {
                float pv = exp2f(sc[nf][r] * SC - mrow[r]);
                rs[r] += pv;
                pb[nf][r] = f2bf(pv);
            }
#pragma unroll
        for (int r = 0; r < 4; ++r) {
            float s = rs[r];
#pragma unroll
            for (int off = 1; off < 16; off <<= 1)
                s += __shfl_xor(s, off, 64);
            lrow[r] = lrow[r] * alpha[r] + s;
        }
#pragma unroll
        for (int df = 0; df < 4; ++df) {
            f32x4 o = O[df];
            o[0] *= alpha[0]; o[1] *= alpha[1]; o[2] *= alpha[2]; o[3] *= alpha[3];
            O[df] = o;
        }
        // ---- P transpose through per-wave LDS (D-layout -> A-layout)
        int buf = (kv0 >> 6) & 1;
#pragma unroll
        for (int nf = 0; nf < 4; ++nf)
#pragma unroll
            for (int r = 0; r < 4; ++r)
                pLds[buf][wave][g * 4 + r][nf * 16 + rw] = pb[nf][r];
        asm volatile("s_waitcnt lgkmcnt(0)" ::: "memory");
        bf16x8 pA0 = *reinterpret_cast<const bf16x8*>(&pLds[buf][wave][rw][g * 8]);
        bf16x8 pA1 = *reinterpret_cast<const bf16x8*>(&pLds[buf][wave][rw][32 + g * 8]);
        // ---- PV
#pragma unroll
        for (int df = 0; df < 4; ++df) {
            bf16x8 v0 = *reinterpret_cast<const bf16x8*>(&Vbh[(size_t)(df * 16 + rw) * GS + kv0 + g * 8]);
            O[df] = __builtin_amdgcn_mfma_f32_16x16x32_bf16(pA0, v0, O[df], 0, 0, 0);
        }
#pragma unroll
        for (int df = 0; df < 4; ++df) {
            bf16x8 v1 = *reinterpret_cast<const bf16x8*>(&Vbh[(size_t)(df * 16 + rw) * GS + kv0 + 32 + g * 8]);
            O[df] = __builtin_amdgcn_mfma_f32_16x16x32_bf16(pA1, v1, O[df], 0, 0, 0);
        }
    }

    const int b = bh >> 4, h = bh & 15;
#pragma unroll
    for (int df = 0; df < 4; ++df)
#pragma unroll
        for (int r = 0; r < 4; ++r) {
            float o = O[df][r] / lrow[r];
            int s = q0 + g * 4 + r;
            int d = h * 64 + df * 16 + rw;
            ctx[((size_t)(b * GS + s)) * GE + d] = f2bf(o);
        }
}

// ---------------------------------------------------------------- launcher
extern "C" void kernel_launch(void* const* d_in, const int* in_sizes, int n_in,
                              void* d_out, int out_size, void* d_ws, size_t ws_size,
                              hipStream_t stream) {
    (void)in_sizes; (void)n_in; (void)out_size; (void)ws_size;

    const float* x  = (const float*)d_in[0];
    const float* Wq = (const float*)d_in[1];
    const float* bq = (const float*)d_in[2];
    const float* Wk = (const float*)d_in[3];
    const float* bk = (const float*)d_in[4];
    const float* Wv = (const float*)d_in[5];
    const float* bv = (const float*)d_in[6];
    const float* Wo = (const float*)d_in[7];
    const float* bo = (const float*)d_in[8];
    float* out = (float*)d_out;

    char* ws = (char*)d_ws;
    u16* xb  = (u16*)(ws);                    // 8 MB  [4096,1024]
    u16* wqb = (u16*)(ws + (8ll  << 20));     // 2 MB
    u16* wkb = (u16*)(ws + (10ll << 20));     // 2 MB
    u16* wvb = (u16*)(ws + (12ll << 20));     // 2 MB
    u16* wob = (u16*)(ws + (14ll << 20));     // 2 MB
    u16* Qb  = (u16*)(ws + (16ll << 20));     // 8 MB  [B,H,S,D]
    u16* Kb  = (u16*)(ws + (24ll << 20));     // 8 MB  [B,H,S,D]
    u16* VTb = (u16*)(ws + (32ll << 20));     // 8 MB  [B,H,D,S]
    u16* ctx = (u16*)(ws + (40ll << 20));     // 8 MB  [B,S,E]

    cvt_kernel<<<2048, 256, 0, stream>>>(x,  xb,  GM * GE);
    cvt_kernel<<<1024, 256, 0, stream>>>(Wq, wqb, GE * GE);
    cvt_kernel<<<1024, 256, 0, stream>>>(Wk, wkb, GE * GE);
    cvt_kernel<<<1024, 256, 0, stream>>>(Wv, wvb, GE * GE);
    cvt_kernel<<<1024, 256, 0, stream>>>(Wo, wob, GE * GE);

    dim3 ggrid(GE / 128, GM / 128);           // (8, 32)
    gemm_bt<0><<<ggrid, 256, 0, stream>>>(xb, wqb, bq, Qb);
    gemm_bt<0><<<ggrid, 256, 0, stream>>>(xb, wkb, bk, Kb);
    gemm_bt<1><<<ggrid, 256, 0, stream>>>(xb, wvb, bv, VTb);

    attn_kernel<<<dim3(GS / 64, GB * GH), 256, 0, stream>>>(Qb, Kb, VTb, ctx);

    gemm_bt<2><<<ggrid, 256, 0, stream>>>(ctx, wob, bo, out);
}

// Round 3
// 240.373 us; speedup vs baseline: 1.4574x; 1.4574x over previous
//
#include <hip/hip_runtime.h>

// ---------------------------------------------------------------------------
// Fused MHA block for MI355X (gfx950).
// B=2, S=2048, E=1024, H=16, D=64. f32 in/out, bf16 MFMA internally.
//
//   cvt:     x,Wq,Wk,Wv,Wo  f32 -> bf16 (ws)
//   gemm<0>: Q = x@Wq^T+bq  -> bf16 [B,H,S,D]
//   gemm<0>: K = x@Wk^T+bk  -> bf16 [B,H,S,D]
//   gemm<1>: V = x@Wv^T+bv  -> bf16 [B,H,D,S]   (transposed: PV A-operand)
//   attn:    swapped-operand flash attention -> ctx bf16 [B,S,E]
//   gemm<2>: out = ctx@Wo^T+bo -> f32 d_out
//
// Attention structure (m214-style, 32x32 MFMA, zero LDS):
//   S^T = mfma(K, Q): lane holds 16 scores of ONE q-column -> softmax is
//   in-register + 1 permlane32_swap. P packed via v_cvt_pk_bf16_f32 and
//   redistributed with 4 permlane32_swap into PV B-fragments.
//   O^T = mfma(V^T, P^T): output column layout == softmax state layout.
//
// permlane32_swap semantics (verified vs HK recipe):
//   (a', b') = swap(a, b):  a' = {a[0:31] || b[0:31]},  b' = {a[32:63] || b[32:63]}
//   (upper half of first operand exchanged with lower half of second)
// ---------------------------------------------------------------------------

using u16 = unsigned short;
using u32 = unsigned int;

typedef __bf16 bf16x8 __attribute__((ext_vector_type(8)));
typedef float  f32x4  __attribute__((ext_vector_type(4)));
typedef float  f32x16 __attribute__((ext_vector_type(16)));
typedef u32    u32x4  __attribute__((ext_vector_type(4)));

constexpr int GB = 2;
constexpr int GS = 2048;
constexpr int GH = 16;
constexpr int GD = 64;
constexpr int GE = 1024;
constexpr int GM = GB * GS;   // 4096 rows

__device__ __forceinline__ u16 f2bf(float f) {
    u32 u = __float_as_uint(f);
    u += 0x7FFFu + ((u >> 16) & 1u);   // RTNE
    return (u16)(u >> 16);
}

__device__ __forceinline__ void plswap(u32& a, u32& b) {
#if __has_builtin(__builtin_amdgcn_permlane32_swap)
    auto r = __builtin_amdgcn_permlane32_swap(a, b, false, false);
    a = r[0]; b = r[1];
#else
    asm volatile("v_permlane32_swap_b32 %0, %1" : "+v"(a), "+v"(b));
#endif
}

// value held by partner lane (lane ^ 32)
__device__ __forceinline__ float xchg32(float v) {
    u32 a = __float_as_uint(v), b = a;
    plswap(a, b);
    // a'[hi lanes] = partner (b's low half); b'[lo lanes] = partner (a's high half)
    return __uint_as_float((threadIdx.x & 32) ? a : b);
}

__device__ __forceinline__ u32 cvtpk(float lo, float hi) {
    u32 d;
    asm("v_cvt_pk_bf16_f32 %0, %1, %2" : "=v"(d) : "v"(lo), "v"(hi));
    return d;
}

// ---------------------------------------------------------------- cvt kernel
__global__ void cvt_kernel(const float* __restrict__ in, u16* __restrict__ out, int n) {
    int idx = blockIdx.x * blockDim.x + threadIdx.x;
    int stride = gridDim.x * blockDim.x;
    for (int i = idx * 4; i < n; i += stride * 4) {
        float4 f = *reinterpret_cast<const float4*>(in + i);
        ushort4 o;
        o.x = f2bf(f.x); o.y = f2bf(f.y); o.z = f2bf(f.z); o.w = f2bf(f.w);
        *reinterpret_cast<ushort4*>(out + i) = o;
    }
}

// ---------------------------------------------------------------- GEMM
// C[m,n] = sum_k A[m,k]*W[n,k] + bias[n].
// MODE 0: bf16 out [B,H,S,D]; MODE 1: bf16 out [B,H,D,S]; MODE 2: f32 out [m,n].
template <int MODE>
__global__ __launch_bounds__(256)
void gemm_bt(const u16* __restrict__ A, const u16* __restrict__ Bw,
             const float* __restrict__ bias, void* __restrict__ outp) {
    constexpr int Kd = GE, Nd = GE;
    constexpr int BM = 128, BN = 128, BK = 32, LDP = 40;
    __shared__ u16 As[BM * LDP];
    __shared__ u16 Bs[BN * LDP];

    const int tid = threadIdx.x;
    const int m0 = blockIdx.y * BM;
    const int n0 = blockIdx.x * BN;
    const int wave = tid >> 6, lane = tid & 63;
    const int wm = (wave >> 1) * 64, wn = (wave & 1) * 64;
    const int g = lane >> 4, rw = lane & 15;

    f32x4 acc[4][4] = {};

    for (int kt = 0; kt < Kd; kt += BK) {
        __syncthreads();
#pragma unroll
        for (int it = 0; it < 2; ++it) {
            int c = tid + it * 256;
            int row = c >> 2, kh = c & 3;
            *reinterpret_cast<uint4*>(&As[row * LDP + kh * 8]) =
                *reinterpret_cast<const uint4*>(&A[(size_t)(m0 + row) * Kd + kt + kh * 8]);
            *reinterpret_cast<uint4*>(&Bs[row * LDP + kh * 8]) =
                *reinterpret_cast<const uint4*>(&Bw[(size_t)(n0 + row) * Kd + kt + kh * 8]);
        }
        __syncthreads();

        bf16x8 aF[4], bF[4];
#pragma unroll
        for (int mf = 0; mf < 4; ++mf)
            aF[mf] = *reinterpret_cast<const bf16x8*>(&As[(wm + mf * 16 + rw) * LDP + g * 8]);
#pragma unroll
        for (int nf = 0; nf < 4; ++nf)
            bF[nf] = *reinterpret_cast<const bf16x8*>(&Bs[(wn + nf * 16 + rw) * LDP + g * 8]);
#pragma unroll
        for (int mf = 0; mf < 4; ++mf)
#pragma unroll
            for (int nf = 0; nf < 4; ++nf)
                acc[mf][nf] = __builtin_amdgcn_mfma_f32_16x16x32_bf16(aF[mf], bF[nf], acc[mf][nf], 0, 0, 0);
    }

#pragma unroll
    for (int mf = 0; mf < 4; ++mf)
#pragma unroll
        for (int nf = 0; nf < 4; ++nf)
#pragma unroll
            for (int r = 0; r < 4; ++r) {
                int m = m0 + wm + mf * 16 + g * 4 + r;
                int n = n0 + wn + nf * 16 + rw;
                float v = acc[mf][nf][r] + bias[n];
                if constexpr (MODE == 2) {
                    reinterpret_cast<float*>(outp)[(size_t)m * Nd + n] = v;
                } else {
                    u16 hv = f2bf(v);
                    int b = m >> 11, s = m & (GS - 1);
                    int h = n >> 6, d = n & 63;
                    if constexpr (MODE == 0)
                        reinterpret_cast<u16*>(outp)[(((size_t)(b * GH + h)) * GS + s) * GD + d] = hv;
                    else
                        reinterpret_cast<u16*>(outp)[(((size_t)(b * GH + h)) * GD + d) * GS + s] = hv;
                }
            }
}

// ---------------------------------------------------------------- attention
// 1D grid 512 blocks (XCD-swizzled), 256 threads = 4 waves, each wave owns a
// 32-q tile. kv-tile 32, double-buffered K/V register prefetch, zero LDS.
__global__ __launch_bounds__(256)
void attn_kernel(const u16* __restrict__ Q, const u16* __restrict__ Kp,
                 const u16* __restrict__ VT, u16* __restrict__ ctx) {
    // bijective XCD swizzle: 512 % 8 == 0
    const int wg = (blockIdx.x & 7) * 64 + (blockIdx.x >> 3);
    const int bh = wg >> 4;                    // 4 consecutive bh per XCD
    const int qb = (wg & 15) * 128;
    const int wave = threadIdx.x >> 6;
    const int l31 = threadIdx.x & 31;
    const int hi = (threadIdx.x >> 5) & 1;
    const int q0 = qb + wave * 32;

    const u16* __restrict__ Qbh = Q  + (size_t)bh * GS * GD;
    const u16* __restrict__ Kbh = Kp + (size_t)bh * GS * GD;
    const u16* __restrict__ Vbh = VT + (size_t)bh * GD * GS;

    const u16* Ql = Qbh + (size_t)(q0 + l31) * GD + hi * 8;
    const u16* Kl = Kbh + (size_t)l31 * GD + hi * 8;
    const u16* Vl = Vbh + (size_t)l31 * GS + hi * 8;

    // Q fragments: B-operand of S^T = K·Q^T. lane: col q=l31, k=16s+8hi+j
    bf16x8 qf[4];
#pragma unroll
    for (int s = 0; s < 4; ++s)
        qf[s] = *reinterpret_cast<const bf16x8*>(Ql + 16 * s);

    f32x16 O0 = {}, O1 = {};
    float m = -1e30f, lsum = 0.f;
    const float SC = 0.125f * 1.44269504088896f;   // D^-1/2 * log2(e)

    bf16x8 kA[4], vA[4], kB[4], vB[4];

    auto loadT = [&](bf16x8* kf, bf16x8* vf, int kv0) {
#pragma unroll
        for (int s = 0; s < 4; ++s)
            kf[s] = *reinterpret_cast<const bf16x8*>(Kl + (size_t)kv0 * GD + 16 * s);
#pragma unroll
        for (int b = 0; b < 2; ++b)
#pragma unroll
            for (int s = 0; s < 2; ++s)
                vf[b * 2 + s] = *reinterpret_cast<const bf16x8*>(Vl + (size_t)b * 32 * GS + kv0 + 16 * s);
    };

    auto tile = [&](const bf16x8* kf, const bf16x8* vf) {
        // ---- S^T tile: 32 kv x 32 q
        f32x16 sacc = {};
#pragma unroll
        for (int s = 0; s < 4; ++s)
            sacc = __builtin_amdgcn_mfma_f32_32x32x16_bf16(kf[s], qf[s], sacc, 0, 0, 0);
        // ---- online softmax, per-lane (q = l31); partner lane holds other 16 kv
        float t8[8];
#pragma unroll
        for (int r = 0; r < 8; ++r) t8[r] = fmaxf(sacc[r], sacc[r + 8]);
#pragma unroll
        for (int r = 0; r < 4; ++r) t8[r] = fmaxf(t8[r], t8[r + 4]);
        float mx = fmaxf(fmaxf(t8[0], t8[1]), fmaxf(t8[2], t8[3]));
        mx = fmaxf(mx, xchg32(mx));
        float mn = fmaxf(m, mx * SC);
        float alpha = __builtin_amdgcn_exp2f(m - mn);
        m = mn;
        float p[16];
#pragma unroll
        for (int r = 0; r < 16; ++r)
            p[r] = __builtin_amdgcn_exp2f(fmaf(sacc[r], SC, -mn));
        float s8[8];
#pragma unroll
        for (int r = 0; r < 8; ++r) s8[r] = p[r] + p[r + 8];
#pragma unroll
        for (int r = 0; r < 4; ++r) s8[r] += s8[r + 4];
        float rs = (s8[0] + s8[1]) + (s8[2] + s8[3]);
        rs += xchg32(rs);
        lsum = lsum * alpha + rs;
#pragma unroll
        for (int r = 0; r < 16; ++r) { O0[r] *= alpha; O1[r] *= alpha; }
        // ---- pack P -> PV B-fragments (target: word_m of slice = kv(2m,2m+1))
        // own words: w[i] = kv(2i + 4hi_offset pattern); cross-half redistribute:
        //   plswap(w0,w2): w0 -> slice0.word0, w2 -> slice0.word2
        //   plswap(w1,w3): w1 -> slice0.word1, w3 -> slice0.word3
        u32 w[8];
#pragma unroll
        for (int i = 0; i < 8; ++i) w[i] = cvtpk(p[2 * i], p[2 * i + 1]);
        plswap(w[0], w[2]);
        plswap(w[1], w[3]);
        plswap(w[4], w[6]);
        plswap(w[5], w[7]);
        u32x4 a0 = {w[0], w[1], w[2], w[3]};
        u32x4 a1 = {w[4], w[5], w[6], w[7]};
        bf16x8 pv0 = __builtin_bit_cast(bf16x8, a0);
        bf16x8 pv1 = __builtin_bit_cast(bf16x8, a1);
        // ---- O^T += V^T · P^T
        O0 = __builtin_amdgcn_mfma_f32_32x32x16_bf16(vf[0], pv0, O0, 0, 0, 0);
        O0 = __builtin_amdgcn_mfma_f32_32x32x16_bf16(vf[1], pv1, O0, 0, 0, 0);
        O1 = __builtin_amdgcn_mfma_f32_32x32x16_bf16(vf[2], pv0, O1, 0, 0, 0);
        O1 = __builtin_amdgcn_mfma_f32_32x32x16_bf16(vf[3], pv1, O1, 0, 0, 0);
    };

    loadT(kA, vA, 0);
#pragma unroll 1
    for (int t = 0; t < 64; t += 2) {
        loadT(kB, vB, (t + 1) * 32);
        tile(kA, vA);
        if (t + 2 < 64) loadT(kA, vA, (t + 2) * 32);
        tile(kB, vB);
    }

    // ---- epilogue: O^T[d][q], lane holds col q=l31, rows d=(r&3)+8*(r>>2)+4*hi
    const int bb = bh >> 4, h = bh & 15;
    const float inv = 1.0f / lsum;
    u16* crow = ctx + ((size_t)(bb * GS + q0 + l31)) * GE + h * 64;
#pragma unroll
    for (int g2 = 0; g2 < 4; ++g2) {
        ushort4 st0, st1;
        st0.x = f2bf(O0[4 * g2 + 0] * inv); st0.y = f2bf(O0[4 * g2 + 1] * inv);
        st0.z = f2bf(O0[4 * g2 + 2] * inv); st0.w = f2bf(O0[4 * g2 + 3] * inv);
        st1.x = f2bf(O1[4 * g2 + 0] * inv); st1.y = f2bf(O1[4 * g2 + 1] * inv);
        st1.z = f2bf(O1[4 * g2 + 2] * inv); st1.w = f2bf(O1[4 * g2 + 3] * inv);
        *reinterpret_cast<ushort4*>(crow + 8 * g2 + 4 * hi)      = st0;
        *reinterpret_cast<ushort4*>(crow + 32 + 8 * g2 + 4 * hi) = st1;
    }
}

// ---------------------------------------------------------------- launcher
extern "C" void kernel_launch(void* const* d_in, const int* in_sizes, int n_in,
                              void* d_out, int out_size, void* d_ws, size_t ws_size,
                              hipStream_t stream) {
    (void)in_sizes; (void)n_in; (void)out_size; (void)ws_size;

    const float* x  = (const float*)d_in[0];
    const float* Wq = (const float*)d_in[1];
    const float* bq = (const float*)d_in[2];
    const float* Wk = (const float*)d_in[3];
    const float* bk = (const float*)d_in[4];
    const float* Wv = (const float*)d_in[5];
    const float* bv = (const float*)d_in[6];
    const float* Wo = (const float*)d_in[7];
    const float* bo = (const float*)d_in[8];
    float* out = (float*)d_out;

    char* ws = (char*)d_ws;
    u16* xb  = (u16*)(ws);                    // 8 MB  [4096,1024]
    u16* wqb = (u16*)(ws + (8ll  << 20));
    u16* wkb = (u16*)(ws + (10ll << 20));
    u16* wvb = (u16*)(ws + (12ll << 20));
    u16* wob = (u16*)(ws + (14ll << 20));
    u16* Qb  = (u16*)(ws + (16ll << 20));     // [B,H,S,D]
    u16* Kb  = (u16*)(ws + (24ll << 20));     // [B,H,S,D]
    u16* VTb = (u16*)(ws + (32ll << 20));     // [B,H,D,S]
    u16* ctx = (u16*)(ws + (40ll << 20));     // [B,S,E]

    cvt_kernel<<<2048, 256, 0, stream>>>(x,  xb,  GM * GE);
    cvt_kernel<<<1024, 256, 0, stream>>>(Wq, wqb, GE * GE);
    cvt_kernel<<<1024, 256, 0, stream>>>(Wk, wkb, GE * GE);
    cvt_kernel<<<1024, 256, 0, stream>>>(Wv, wvb, GE * GE);
    cvt_kernel<<<1024, 256, 0, stream>>>(Wo, wob, GE * GE);

    dim3 ggrid(GE / 128, GM / 128);           // (8, 32)
    gemm_bt<0><<<ggrid, 256, 0, stream>>>(xb, wqb, bq, Qb);
    gemm_bt<0><<<ggrid, 256, 0, stream>>>(xb, wkb, bk, Kb);
    gemm_bt<1><<<ggrid, 256, 0, stream>>>(xb, wvb, bv, VTb);

    attn_kernel<<<dim3(512), 256, 0, stream>>>(Qb, Kb, VTb, ctx);

    gemm_bt<2><<<ggrid, 256, 0, stream>>>(ctx, wob, bo, out);
}

// Round 5
// 218.904 us; speedup vs baseline: 1.6004x; 1.0981x over previous
//
#include <hip/hip_runtime.h>

// ---------------------------------------------------------------------------
// Fused MHA block for MI355X (gfx950).
// B=2, S=2048, E=1024, H=16, D=64. f32 in/out, bf16 MFMA internally.
//
//   cvt:      x, {Wq,Wk,Wv,Wo} f32 -> bf16 (ws)
//   qkv_gemm: Q,K -> bf16 [B,H,S,D]; V -> bf16 [B,H,D,S]  (one grid.z=3 dispatch,
//             m97-style global_load_lds staging, 128x64 tile)
//   attn:     swapped-operand flash attention, kv-split 2-way (flash-decoding)
//             -> f32 partials (O^T, m, l) in ws   [falls back to 1-way if ws small]
//   combine:  merge 2 kv-splits -> ctx bf16 [B,S,E]
//   out_gemm: out = ctx@Wo^T+bo -> f32 d_out
//
// Attention (m214-style, 32x32 MFMA, zero LDS):
//   S^T = mfma(K, Q): lane holds 16 scores of ONE q-column; softmax in-register
//   (+1 permlane32_swap). P packed via v_cvt_pk_bf16_f32 + 4 permlane32_swap.
//   O^T = mfma(V^T, P^T). T13 defer-max skips O-rescale unless max grows >8 (log2).
//
// permlane32_swap: a' = {a_lo || b_lo}, b' = {a_hi || b_hi}   (verified R2)
// R3 bug fixed here: partial-O stride is 2048 f32 per (tile,split) — 32q x 64d.
// ---------------------------------------------------------------------------

using u16 = unsigned short;
using u32 = unsigned int;

typedef __bf16 bf16x8 __attribute__((ext_vector_type(8)));
typedef float  f32x4  __attribute__((ext_vector_type(4)));
typedef float  f32x16 __attribute__((ext_vector_type(16)));
typedef u32    u32x4  __attribute__((ext_vector_type(4)));

constexpr int GB = 2;
constexpr int GS = 2048;
constexpr int GH = 16;
constexpr int GD = 64;
constexpr int GE = 1024;
constexpr int GM = GB * GS;      // 4096 rows
constexpr int PSTRIDE = 2048;    // floats per (q-tile, split) partial: 32 q x 64 d

__device__ __forceinline__ u16 f2bf(float f) {
    u32 u = __float_as_uint(f);
    u += 0x7FFFu + ((u >> 16) & 1u);   // RTNE
    return (u16)(u >> 16);
}

__device__ __forceinline__ void plswap(u32& a, u32& b) {
#if __has_builtin(__builtin_amdgcn_permlane32_swap)
    auto r = __builtin_amdgcn_permlane32_swap(a, b, false, false);
    a = r[0]; b = r[1];
#else
    asm volatile("v_permlane32_swap_b32 %0, %1" : "+v"(a), "+v"(b));
#endif
}

// value held by partner lane (lane ^ 32)
__device__ __forceinline__ float xchg32(float v) {
    u32 a = __float_as_uint(v), b = a;
    plswap(a, b);
    return __uint_as_float((threadIdx.x & 32) ? a : b);
}

__device__ __forceinline__ u32 cvtpk(float lo, float hi) {
    u32 d;
    asm("v_cvt_pk_bf16_f32 %0, %1, %2" : "=v"(d) : "v"(lo), "v"(hi));
    return d;
}

// async global -> LDS, 16 B per lane (linear dest: base + lane*16)
__device__ __forceinline__ void gl_lds16(const u16* g, u16* l) {
#if __has_builtin(__builtin_amdgcn_global_load_lds)
    __builtin_amdgcn_global_load_lds(
        (const __attribute__((address_space(1))) void*)g,
        (__attribute__((address_space(3))) void*)l, 16, 0, 0);
#else
    *reinterpret_cast<uint4*>(l) = *reinterpret_cast<const uint4*>(g);
#endif
}

// ---------------------------------------------------------------- cvt kernels
__global__ void cvt_kernel(const float* __restrict__ in, u16* __restrict__ out, int n) {
    int idx = blockIdx.x * blockDim.x + threadIdx.x;
    int stride = gridDim.x * blockDim.x;
    for (int i = idx * 4; i < n; i += stride * 4) {
        float4 f = *reinterpret_cast<const float4*>(in + i);
        ushort4 o;
        o.x = f2bf(f.x); o.y = f2bf(f.y); o.z = f2bf(f.z); o.w = f2bf(f.w);
        *reinterpret_cast<ushort4*>(out + i) = o;
    }
}

__global__ void cvtw_kernel(const float* __restrict__ w0, const float* __restrict__ w1,
                            const float* __restrict__ w2, const float* __restrict__ w3,
                            u16* __restrict__ o0, u16* __restrict__ o1,
                            u16* __restrict__ o2, u16* __restrict__ o3) {
    const float* in = blockIdx.y == 0 ? w0 : blockIdx.y == 1 ? w1 : blockIdx.y == 2 ? w2 : w3;
    u16* out = blockIdx.y == 0 ? o0 : blockIdx.y == 1 ? o1 : blockIdx.y == 2 ? o2 : o3;
    int idx = blockIdx.x * blockDim.x + threadIdx.x;
    int stride = gridDim.x * blockDim.x;
    for (int i = idx * 4; i < GE * GE; i += stride * 4) {
        float4 f = *reinterpret_cast<const float4*>(in + i);
        ushort4 o;
        o.x = f2bf(f.x); o.y = f2bf(f.y); o.z = f2bf(f.z); o.w = f2bf(f.w);
        *reinterpret_cast<ushort4*>(out + i) = o;
    }
}

// ---------------------------------------------------------------- GEMM core
// 128x64 tile, BK=32, global_load_lds staging, 4 waves each 64x32 out.
// C[m,n] = sum_k A[m,k]*W[n,k] + bias[n].

// QKV: grid (16, 32, 3). z=0 -> Q [B,H,S,D], z=1 -> K [B,H,S,D], z=2 -> V [B,H,D,S].
__global__ __launch_bounds__(256)
void qkv_gemm(const u16* __restrict__ A,
              const u16* __restrict__ wq, const u16* __restrict__ wk, const u16* __restrict__ wv,
              const float* __restrict__ bq, const float* __restrict__ bk, const float* __restrict__ bv,
              u16* __restrict__ Qb, u16* __restrict__ Kb, u16* __restrict__ VTb) {
    constexpr int Kd = GE;
    constexpr int BM = 128, BN = 64, BK = 32;
    __shared__ u16 As[BM * BK];
    __shared__ u16 Bs[BN * BK];

    const int z = blockIdx.z;
    const u16* __restrict__ Bw = z == 0 ? wq : z == 1 ? wk : wv;
    const float* __restrict__ bias = z == 0 ? bq : z == 1 ? bk : bv;
    u16* __restrict__ outp = z == 0 ? Qb : z == 1 ? Kb : VTb;

    const int tid = threadIdx.x;
    const int m0 = blockIdx.y * BM;
    const int n0 = blockIdx.x * BN;
    const int wave = tid >> 6, lane = tid & 63;
    const int wm = (wave >> 1) * 64, wn = (wave & 1) * 32;
    const int g = lane >> 4, rw = lane & 15;
    const int lr = lane >> 2, lc = (lane & 3) * 8;   // staging row/col within chunk

    f32x4 acc[4][2] = {};

    for (int kt = 0; kt < Kd; kt += BK) {
        __syncthreads();
        gl_lds16(&A [(size_t)(m0 + wave * 16 + lr) * Kd + kt + lc], &As[(wave * 16 + lr) * BK + lc]);
        gl_lds16(&A [(size_t)(m0 + (wave + 4) * 16 + lr) * Kd + kt + lc], &As[((wave + 4) * 16 + lr) * BK + lc]);
        gl_lds16(&Bw[(size_t)(n0 + wave * 16 + lr) * Kd + kt + lc], &Bs[(wave * 16 + lr) * BK + lc]);
        __syncthreads();

        bf16x8 aF[4], bF[2];
#pragma unroll
        for (int mf = 0; mf < 4; ++mf)
            aF[mf] = *reinterpret_cast<const bf16x8*>(&As[(wm + mf * 16 + rw) * BK + g * 8]);
#pragma unroll
        for (int nf = 0; nf < 2; ++nf)
            bF[nf] = *reinterpret_cast<const bf16x8*>(&Bs[(wn + nf * 16 + rw) * BK + g * 8]);
#pragma unroll
        for (int mf = 0; mf < 4; ++mf)
#pragma unroll
            for (int nf = 0; nf < 2; ++nf)
                acc[mf][nf] = __builtin_amdgcn_mfma_f32_16x16x32_bf16(aF[mf], bF[nf], acc[mf][nf], 0, 0, 0);
    }

#pragma unroll
    for (int mf = 0; mf < 4; ++mf)
#pragma unroll
        for (int nf = 0; nf < 2; ++nf)
#pragma unroll
            for (int r = 0; r < 4; ++r) {
                int m = m0 + wm + mf * 16 + g * 4 + r;
                int n = n0 + wn + nf * 16 + rw;
                u16 hv = f2bf(acc[mf][nf][r] + bias[n]);
                int b = m >> 11, s = m & (GS - 1);
                int h = n >> 6, d = n & 63;
                if (z == 2)
                    outp[(((size_t)(b * GH + h)) * GD + d) * GS + s] = hv;
                else
                    outp[(((size_t)(b * GH + h)) * GS + s) * GD + d] = hv;
            }
}

// out-projection: f32 out [m, n]. grid (16, 32).
__global__ __launch_bounds__(256)
void out_gemm(const u16* __restrict__ A, const u16* __restrict__ Bw,
              const float* __restrict__ bias, float* __restrict__ outp) {
    constexpr int Kd = GE, Nd = GE;
    constexpr int BM = 128, BN = 64, BK = 32;
    __shared__ u16 As[BM * BK];
    __shared__ u16 Bs[BN * BK];

    const int tid = threadIdx.x;
    const int m0 = blockIdx.y * BM;
    const int n0 = blockIdx.x * BN;
    const int wave = tid >> 6, lane = tid & 63;
    const int wm = (wave >> 1) * 64, wn = (wave & 1) * 32;
    const int g = lane >> 4, rw = lane & 15;
    const int lr = lane >> 2, lc = (lane & 3) * 8;

    f32x4 acc[4][2] = {};

    for (int kt = 0; kt < Kd; kt += BK) {
        __syncthreads();
        gl_lds16(&A [(size_t)(m0 + wave * 16 + lr) * Kd + kt + lc], &As[(wave * 16 + lr) * BK + lc]);
        gl_lds16(&A [(size_t)(m0 + (wave + 4) * 16 + lr) * Kd + kt + lc], &As[((wave + 4) * 16 + lr) * BK + lc]);
        gl_lds16(&Bw[(size_t)(n0 + wave * 16 + lr) * Kd + kt + lc], &Bs[(wave * 16 + lr) * BK + lc]);
        __syncthreads();

        bf16x8 aF[4], bF[2];
#pragma unroll
        for (int mf = 0; mf < 4; ++mf)
            aF[mf] = *reinterpret_cast<const bf16x8*>(&As[(wm + mf * 16 + rw) * BK + g * 8]);
#pragma unroll
        for (int nf = 0; nf < 2; ++nf)
            bF[nf] = *reinterpret_cast<const bf16x8*>(&Bs[(wn + nf * 16 + rw) * BK + g * 8]);
#pragma unroll
        for (int mf = 0; mf < 4; ++mf)
#pragma unroll
            for (int nf = 0; nf < 2; ++nf)
                acc[mf][nf] = __builtin_amdgcn_mfma_f32_16x16x32_bf16(aF[mf], bF[nf], acc[mf][nf], 0, 0, 0);
    }

#pragma unroll
    for (int mf = 0; mf < 4; ++mf)
#pragma unroll
        for (int nf = 0; nf < 2; ++nf)
#pragma unroll
            for (int r = 0; r < 4; ++r) {
                int m = m0 + wm + mf * 16 + g * 4 + r;
                int n = n0 + wn + nf * 16 + rw;
                outp[(size_t)m * Nd + n] = acc[mf][nf][r] + bias[n];
            }
}

// ---------------------------------------------------------------- attention
// NSPLIT=2: grid 1024 blocks, each wave does 32 q x 1024 kv, writes partials.
// NSPLIT=1: grid 512 blocks, full kv range, writes ctx directly.
template <int NSPLIT>
__global__ __launch_bounds__(256)
void attn_kernel(const u16* __restrict__ Q, const u16* __restrict__ Kp,
                 const u16* __restrict__ VT, u16* __restrict__ ctx,
                 float* __restrict__ Opart, float* __restrict__ Mpart,
                 float* __restrict__ Lpart) {
    int bh, qb, split;
    if (NSPLIT == 2) {
        const int wg = (blockIdx.x & 7) * 128 + (blockIdx.x >> 3);   // bijective, 1024%8==0
        bh = wg >> 5;
        split = wg & 1;
        qb = ((wg >> 1) & 15) * 128;
    } else {
        const int wg = (blockIdx.x & 7) * 64 + (blockIdx.x >> 3);
        bh = wg >> 4;
        split = 0;
        qb = (wg & 15) * 128;
    }
    const int wave = threadIdx.x >> 6;
    const int l31 = threadIdx.x & 31;
    const int hi = (threadIdx.x >> 5) & 1;
    const int q0 = qb + wave * 32;
    constexpr int KVLEN = GS / NSPLIT;
    constexpr int NT = KVLEN / 32;
    const int kvbase = split * KVLEN;

    const u16* __restrict__ Qbh = Q  + (size_t)bh * GS * GD;
    const u16* __restrict__ Kbh = Kp + (size_t)bh * GS * GD;
    const u16* __restrict__ Vbh = VT + (size_t)bh * GD * GS;

    const u16* Ql = Qbh + (size_t)(q0 + l31) * GD + hi * 8;
    const u16* Kl = Kbh + (size_t)(kvbase + l31) * GD + hi * 8;
    const u16* Vl = Vbh + (size_t)l31 * GS + kvbase + hi * 8;

    // Q fragments: B-operand of S^T = K.Q^T. lane: col q=l31, k=16s+8hi+j
    bf16x8 qf[4];
#pragma unroll
    for (int s = 0; s < 4; ++s)
        qf[s] = *reinterpret_cast<const bf16x8*>(Ql + 16 * s);

    f32x16 O0 = {}, O1 = {};
    float m = -1e30f, lsum = 0.f;
    const float SC = 0.125f * 1.44269504088896f;   // D^-1/2 * log2(e)

    bf16x8 kA[4], vA[4], kB[4], vB[4];

    auto loadT = [&](bf16x8* kf, bf16x8* vf, int kv0) {
#pragma unroll
        for (int s = 0; s < 4; ++s)
            kf[s] = *reinterpret_cast<const bf16x8*>(Kl + (size_t)kv0 * GD + 16 * s);
#pragma unroll
        for (int b = 0; b < 2; ++b)
#pragma unroll
            for (int s = 0; s < 2; ++s)
                vf[b * 2 + s] = *reinterpret_cast<const bf16x8*>(Vl + (size_t)b * 32 * GS + kv0 + 16 * s);
    };

    auto tile = [&](const bf16x8* kf, const bf16x8* vf) {
        // ---- S^T tile: 32 kv x 32 q
        f32x16 sacc = {};
        __builtin_amdgcn_s_setprio(1);
#pragma unroll
        for (int s = 0; s < 4; ++s)
            sacc = __builtin_amdgcn_mfma_f32_32x32x16_bf16(kf[s], qf[s], sacc, 0, 0, 0);
        __builtin_amdgcn_s_setprio(0);
        // ---- online softmax, per-lane (q = l31); partner lane holds other 16 kv
        float t8[8];
#pragma unroll
        for (int r = 0; r < 8; ++r) t8[r] = fmaxf(sacc[r], sacc[r + 8]);
#pragma unroll
        for (int r = 0; r < 4; ++r) t8[r] = fmaxf(t8[r], t8[r + 4]);
        float mx = fmaxf(fmaxf(t8[0], t8[1]), fmaxf(t8[2], t8[3]));
        mx = fmaxf(mx, xchg32(mx));
        float mxs = mx * SC;
        // T13 defer-max: rescale only if any q-row's max grew past m+8 (log2 units)
        if (__any(mxs > m + 8.f)) {
            float mn = fmaxf(m, mxs);
            float alpha = __builtin_amdgcn_exp2f(m - mn);
            m = mn;
            lsum *= alpha;
#pragma unroll
            for (int r = 0; r < 16; ++r) { O0[r] *= alpha; O1[r] *= alpha; }
        }
        float p[16];
#pragma unroll
        for (int r = 0; r < 16; ++r)
            p[r] = __builtin_amdgcn_exp2f(fmaf(sacc[r], SC, -m));
        float s8[8];
#pragma unroll
        for (int r = 0; r < 8; ++r) s8[r] = p[r] + p[r + 8];
#pragma unroll
        for (int r = 0; r < 4; ++r) s8[r] += s8[r + 4];
        float rs = (s8[0] + s8[1]) + (s8[2] + s8[3]);
        rs += xchg32(rs);
        lsum += rs;
        // ---- pack P -> PV B-fragments
        u32 w[8];
#pragma unroll
        for (int i = 0; i < 8; ++i) w[i] = cvtpk(p[2 * i], p[2 * i + 1]);
        plswap(w[0], w[2]);
        plswap(w[1], w[3]);
        plswap(w[4], w[6]);
        plswap(w[5], w[7]);
        u32x4 a0 = {w[0], w[1], w[2], w[3]};
        u32x4 a1 = {w[4], w[5], w[6], w[7]};
        bf16x8 pv0 = __builtin_bit_cast(bf16x8, a0);
        bf16x8 pv1 = __builtin_bit_cast(bf16x8, a1);
        // ---- O^T += V^T . P^T
        __builtin_amdgcn_s_setprio(1);
        O0 = __builtin_amdgcn_mfma_f32_32x32x16_bf16(vf[0], pv0, O0, 0, 0, 0);
        O0 = __builtin_amdgcn_mfma_f32_32x32x16_bf16(vf[1], pv1, O0, 0, 0, 0);
        O1 = __builtin_amdgcn_mfma_f32_32x32x16_bf16(vf[2], pv0, O1, 0, 0, 0);
        O1 = __builtin_amdgcn_mfma_f32_32x32x16_bf16(vf[3], pv1, O1, 0, 0, 0);
        __builtin_amdgcn_s_setprio(0);
    };

    loadT(kA, vA, 0);
#pragma unroll 1
    for (int t = 0; t < NT; t += 2) {
        loadT(kB, vB, (t + 1) * 32);
        tile(kA, vA);
        if (t + 2 < NT) loadT(kA, vA, (t + 2) * 32);
        tile(kB, vB);
    }

    if (NSPLIT == 2) {
        // partials: O^T unnormalized + (m, lsum). wt = global 32-q tile index.
        const int wt = bh * 64 + (q0 >> 5);
        const size_t base = ((size_t)wt * 2 + split) * PSTRIDE;
#pragma unroll
        for (int r = 0; r < 16; ++r) {
            int d = (r & 3) + 8 * (r >> 2) + 4 * hi;
            Opart[base + (size_t)d * 32 + l31]        = O0[r];
            Opart[base + (size_t)(d + 32) * 32 + l31] = O1[r];
        }
        if (hi == 0) {
            Mpart[(wt * 2 + split) * 32 + l31] = m;
            Lpart[(wt * 2 + split) * 32 + l31] = lsum;
        }
    } else {
        const int bb = bh >> 4, h = bh & 15;
        const float inv = 1.0f / lsum;
        u16* crow = ctx + ((size_t)(bb * GS + q0 + l31)) * GE + h * 64;
#pragma unroll
        for (int g2 = 0; g2 < 4; ++g2) {
            ushort4 st0, st1;
            st0.x = f2bf(O0[4 * g2 + 0] * inv); st0.y = f2bf(O0[4 * g2 + 1] * inv);
            st0.z = f2bf(O0[4 * g2 + 2] * inv); st0.w = f2bf(O0[4 * g2 + 3] * inv);
            st1.x = f2bf(O1[4 * g2 + 0] * inv); st1.y = f2bf(O1[4 * g2 + 1] * inv);
            st1.z = f2bf(O1[4 * g2 + 2] * inv); st1.w = f2bf(O1[4 * g2 + 3] * inv);
            *reinterpret_cast<ushort4*>(crow + 8 * g2 + 4 * hi)      = st0;
            *reinterpret_cast<ushort4*>(crow + 32 + 8 * g2 + 4 * hi) = st1;
        }
    }
}

// ---------------------------------------------------------------- combine
// grid 2048 (one per 32-q tile), 256 threads: q = t&31, d-block = t>>5 (8 d each).
__global__ __launch_bounds__(256)
void combine_kernel(const float* __restrict__ Opart, const float* __restrict__ Mpart,
                    const float* __restrict__ Lpart, u16* __restrict__ ctx) {
    const int wt = blockIdx.x;
    const int bh = wt >> 6, bb = bh >> 4, h = bh & 15;
    const int q0 = (wt & 63) * 32;
    const int q = threadIdx.x & 31, db = threadIdx.x >> 5;
    const size_t b0 = (size_t)wt * 2 * PSTRIDE, b1 = b0 + PSTRIDE;

    float m0 = Mpart[(wt * 2 + 0) * 32 + q], m1 = Mpart[(wt * 2 + 1) * 32 + q];
    float l0 = Lpart[(wt * 2 + 0) * 32 + q], l1 = Lpart[(wt * 2 + 1) * 32 + q];
    float M = fmaxf(m0, m1);
    float c0 = exp2f(m0 - M), c1 = exp2f(m1 - M);
    float inv = 1.f / (c0 * l0 + c1 * l1);
    c0 *= inv; c1 *= inv;

    u16* crow = ctx + ((size_t)(bb * GS + q0 + q)) * GE + h * 64 + db * 8;
    ushort4 s0, s1;
    float o[8];
#pragma unroll
    for (int i = 0; i < 8; ++i) {
        int d = db * 8 + i;
        o[i] = c0 * Opart[b0 + (size_t)d * 32 + q] + c1 * Opart[b1 + (size_t)d * 32 + q];
    }
    s0.x = f2bf(o[0]); s0.y = f2bf(o[1]); s0.z = f2bf(o[2]); s0.w = f2bf(o[3]);
    s1.x = f2bf(o[4]); s1.y = f2bf(o[5]); s1.z = f2bf(o[6]); s1.w = f2bf(o[7]);
    *reinterpret_cast<ushort4*>(crow)     = s0;
    *reinterpret_cast<ushort4*>(crow + 4) = s1;
}

// ---------------------------------------------------------------- launcher
extern "C" void kernel_launch(void* const* d_in, const int* in_sizes, int n_in,
                              void* d_out, int out_size, void* d_ws, size_t ws_size,
                              hipStream_t stream) {
    (void)in_sizes; (void)n_in; (void)out_size;

    const float* x  = (const float*)d_in[0];
    const float* Wq = (const float*)d_in[1];
    const float* bq = (const float*)d_in[2];
    const float* Wk = (const float*)d_in[3];
    const float* bk = (const float*)d_in[4];
    const float* Wv = (const float*)d_in[5];
    const float* bv = (const float*)d_in[6];
    const float* Wo = (const float*)d_in[7];
    const float* bo = (const float*)d_in[8];
    float* out = (float*)d_out;

    char* ws = (char*)d_ws;
    u16* xb  = (u16*)(ws);                    // 8 MB  [4096,1024]
    u16* wqb = (u16*)(ws + (8ll  << 20));
    u16* wkb = (u16*)(ws + (10ll << 20));
    u16* wvb = (u16*)(ws + (12ll << 20));
    u16* wob = (u16*)(ws + (14ll << 20));
    u16* Qb  = (u16*)(ws + (16ll << 20));     // [B,H,S,D]
    u16* Kb  = (u16*)(ws + (24ll << 20));     // [B,H,S,D]
    u16* VTb = (u16*)(ws + (32ll << 20));     // [B,H,D,S]
    u16* ctx = (u16*)(ws + (40ll << 20));     // [B,S,E]
    float* Opart = (float*)(ws + (48ll << 20));   // 32 MB: 2048 tiles x 2 x 2048 f32
    float* Mpart = (float*)(ws + (80ll << 20));   // 0.5 MB
    float* Lpart = (float*)(ws + (80ll << 20) + (512ll << 10));
    const bool split2 = ws_size >= (81ll << 20);

    cvt_kernel<<<2048, 256, 0, stream>>>(x, xb, GM * GE);
    cvtw_kernel<<<dim3(512, 4), 256, 0, stream>>>(Wq, Wk, Wv, Wo, wqb, wkb, wvb, wob);

    qkv_gemm<<<dim3(GE / 64, GM / 128, 3), 256, 0, stream>>>(
        xb, wqb, wkb, wvb, bq, bk, bv, Qb, Kb, VTb);

    if (split2) {
        attn_kernel<2><<<dim3(1024), 256, 0, stream>>>(Qb, Kb, VTb, ctx, Opart, Mpart, Lpart);
        combine_kernel<<<dim3(2048), 256, 0, stream>>>(Opart, Mpart, Lpart, ctx);
    } else {
        attn_kernel<1><<<dim3(512), 256, 0, stream>>>(Qb, Kb, VTb, ctx, Opart, Mpart, Lpart);
    }

    out_gemm<<<dim3(GE / 64, GM / 128), 256, 0, stream>>>(ctx, wob, bo, out);
}

// Round 6
// 159.161 us; speedup vs baseline: 2.2011x; 1.3754x over previous
//
#include <hip/hip_runtime.h>

// ---------------------------------------------------------------------------
// Fused MHA block for MI355X (gfx950).
// B=2, S=2048, E=1024, H=16, D=64. f32 in/out, bf16 MFMA internally.
//
//   cvt:      x, {Wq,Wk,Wv,Wo} f32 -> bf16 (ws)
//   qkv_gemm: Q,K -> bf16 [B,H,S,D]; V -> bf16 [B,H,D,S]  (grid.z=3, gload_lds)
//   attn:     swapped-operand flash attention, kv-split 2, KVBLK=64,
//             K/V staged in XOR-swizzled LDS shared by 4 waves (m214 structure)
//   combine:  merge 2 kv-splits -> ctx bf16 [B,S,E]
//   out_gemm: out = ctx@Wo^T+bo -> f32 d_out
//
// Attention per step (per block: 128 q x 64 kv):
//   stage(next buf): global_load_lds 16B/lane, LINEAR dest; source address
//   pre-swizzled chunk^=(row&7) so swizzled ds_read retrieves correctly (T2).
//   S^T = mfma(K,Q) x2 subtiles; in-register softmax over 32 scores/lane
//   (1 permlane32_swap); P via v_cvt_pk_bf16_f32 + plswap; O^T = mfma(V^T,P^T).
//
// permlane32_swap: a' = {a_lo || b_lo}, b' = {a_hi || b_hi}   (verified R2)
// ---------------------------------------------------------------------------

using u16 = unsigned short;
using u32 = unsigned int;

typedef __bf16 bf16x8 __attribute__((ext_vector_type(8)));
typedef float  f32x4  __attribute__((ext_vector_type(4)));
typedef float  f32x16 __attribute__((ext_vector_type(16)));
typedef u32    u32x4  __attribute__((ext_vector_type(4)));

constexpr int GB = 2;
constexpr int GS = 2048;
constexpr int GH = 16;
constexpr int GD = 64;
constexpr int GE = 1024;
constexpr int GM = GB * GS;      // 4096 rows
constexpr int PSTRIDE = 2048;    // floats per (q-tile, split) partial: 32 q x 64 d

__device__ __forceinline__ u16 f2bf(float f) {
    u32 u = __float_as_uint(f);
    u += 0x7FFFu + ((u >> 16) & 1u);   // RTNE
    return (u16)(u >> 16);
}

__device__ __forceinline__ void plswap(u32& a, u32& b) {
#if __has_builtin(__builtin_amdgcn_permlane32_swap)
    auto r = __builtin_amdgcn_permlane32_swap(a, b, false, false);
    a = r[0]; b = r[1];
#else
    asm volatile("v_permlane32_swap_b32 %0, %1" : "+v"(a), "+v"(b));
#endif
}

__device__ __forceinline__ float xchg32(float v) {
    u32 a = __float_as_uint(v), b = a;
    plswap(a, b);
    return __uint_as_float((threadIdx.x & 32) ? a : b);
}

__device__ __forceinline__ u32 cvtpk(float lo, float hi) {
    u32 d;
    asm("v_cvt_pk_bf16_f32 %0, %1, %2" : "=v"(d) : "v"(lo), "v"(hi));
    return d;
}

// async global -> LDS, 16 B per lane (linear dest: base + lane*16)
__device__ __forceinline__ void gl_lds16(const u16* g, u16* l) {
#if __has_builtin(__builtin_amdgcn_global_load_lds)
    __builtin_amdgcn_global_load_lds(
        (const __attribute__((address_space(1))) void*)g,
        (__attribute__((address_space(3))) void*)l, 16, 0, 0);
#else
    *reinterpret_cast<uint4*>(l) = *reinterpret_cast<const uint4*>(g);
#endif
}

// ---------------------------------------------------------------- cvt kernels
__global__ void cvt_kernel(const float* __restrict__ in, u16* __restrict__ out, int n) {
    int idx = blockIdx.x * blockDim.x + threadIdx.x;
    int stride = gridDim.x * blockDim.x;
    for (int i = idx * 4; i < n; i += stride * 4) {
        float4 f = *reinterpret_cast<const float4*>(in + i);
        ushort4 o;
        o.x = f2bf(f.x); o.y = f2bf(f.y); o.z = f2bf(f.z); o.w = f2bf(f.w);
        *reinterpret_cast<ushort4*>(out + i) = o;
    }
}

__global__ void cvtw_kernel(const float* __restrict__ w0, const float* __restrict__ w1,
                            const float* __restrict__ w2, const float* __restrict__ w3,
                            u16* __restrict__ o0, u16* __restrict__ o1,
                            u16* __restrict__ o2, u16* __restrict__ o3) {
    const float* in = blockIdx.y == 0 ? w0 : blockIdx.y == 1 ? w1 : blockIdx.y == 2 ? w2 : w3;
    u16* out = blockIdx.y == 0 ? o0 : blockIdx.y == 1 ? o1 : blockIdx.y == 2 ? o2 : o3;
    int idx = blockIdx.x * blockDim.x + threadIdx.x;
    int stride = gridDim.x * blockDim.x;
    for (int i = idx * 4; i < GE * GE; i += stride * 4) {
        float4 f = *reinterpret_cast<const float4*>(in + i);
        ushort4 o;
        o.x = f2bf(f.x); o.y = f2bf(f.y); o.z = f2bf(f.z); o.w = f2bf(f.w);
        *reinterpret_cast<ushort4*>(out + i) = o;
    }
}

// ---------------------------------------------------------------- GEMM core
// (frozen from R4) 128x64 tile, BK=32, global_load_lds staging.
__global__ __launch_bounds__(256)
void qkv_gemm(const u16* __restrict__ A,
              const u16* __restrict__ wq, const u16* __restrict__ wk, const u16* __restrict__ wv,
              const float* __restrict__ bq, const float* __restrict__ bk, const float* __restrict__ bv,
              u16* __restrict__ Qb, u16* __restrict__ Kb, u16* __restrict__ VTb) {
    constexpr int Kd = GE;
    constexpr int BM = 128, BN = 64, BK = 32;
    __shared__ u16 As[BM * BK];
    __shared__ u16 Bs[BN * BK];

    const int z = blockIdx.z;
    const u16* __restrict__ Bw = z == 0 ? wq : z == 1 ? wk : wv;
    const float* __restrict__ bias = z == 0 ? bq : z == 1 ? bk : bv;
    u16* __restrict__ outp = z == 0 ? Qb : z == 1 ? Kb : VTb;

    const int tid = threadIdx.x;
    const int m0 = blockIdx.y * BM;
    const int n0 = blockIdx.x * BN;
    const int wave = tid >> 6, lane = tid & 63;
    const int wm = (wave >> 1) * 64, wn = (wave & 1) * 32;
    const int g = lane >> 4, rw = lane & 15;
    const int lr = lane >> 2, lc = (lane & 3) * 8;

    f32x4 acc[4][2] = {};

    for (int kt = 0; kt < Kd; kt += BK) {
        __syncthreads();
        gl_lds16(&A [(size_t)(m0 + wave * 16 + lr) * Kd + kt + lc], &As[(wave * 16 + lr) * BK + lc]);
        gl_lds16(&A [(size_t)(m0 + (wave + 4) * 16 + lr) * Kd + kt + lc], &As[((wave + 4) * 16 + lr) * BK + lc]);
        gl_lds16(&Bw[(size_t)(n0 + wave * 16 + lr) * Kd + kt + lc], &Bs[(wave * 16 + lr) * BK + lc]);
        __syncthreads();

        bf16x8 aF[4], bF[2];
#pragma unroll
        for (int mf = 0; mf < 4; ++mf)
            aF[mf] = *reinterpret_cast<const bf16x8*>(&As[(wm + mf * 16 + rw) * BK + g * 8]);
#pragma unroll
        for (int nf = 0; nf < 2; ++nf)
            bF[nf] = *reinterpret_cast<const bf16x8*>(&Bs[(wn + nf * 16 + rw) * BK + g * 8]);
#pragma unroll
        for (int mf = 0; mf < 4; ++mf)
#pragma unroll
            for (int nf = 0; nf < 2; ++nf)
                acc[mf][nf] = __builtin_amdgcn_mfma_f32_16x16x32_bf16(aF[mf], bF[nf], acc[mf][nf], 0, 0, 0);
    }

#pragma unroll
    for (int mf = 0; mf < 4; ++mf)
#pragma unroll
        for (int nf = 0; nf < 2; ++nf)
#pragma unroll
            for (int r = 0; r < 4; ++r) {
                int m = m0 + wm + mf * 16 + g * 4 + r;
                int n = n0 + wn + nf * 16 + rw;
                u16 hv = f2bf(acc[mf][nf][r] + bias[n]);
                int b = m >> 11, s = m & (GS - 1);
                int h = n >> 6, d = n & 63;
                if (z == 2)
                    outp[(((size_t)(b * GH + h)) * GD + d) * GS + s] = hv;
                else
                    outp[(((size_t)(b * GH + h)) * GS + s) * GD + d] = hv;
            }
}

__global__ __launch_bounds__(256)
void out_gemm(const u16* __restrict__ A, const u16* __restrict__ Bw,
              const float* __restrict__ bias, float* __restrict__ outp) {
    constexpr int Kd = GE, Nd = GE;
    constexpr int BM = 128, BN = 64, BK = 32;
    __shared__ u16 As[BM * BK];
    __shared__ u16 Bs[BN * BK];

    const int tid = threadIdx.x;
    const int m0 = blockIdx.y * BM;
    const int n0 = blockIdx.x * BN;
    const int wave = tid >> 6, lane = tid & 63;
    const int wm = (wave >> 1) * 64, wn = (wave & 1) * 32;
    const int g = lane >> 4, rw = lane & 15;
    const int lr = lane >> 2, lc = (lane & 3) * 8;

    f32x4 acc[4][2] = {};

    for (int kt = 0; kt < Kd; kt += BK) {
        __syncthreads();
        gl_lds16(&A [(size_t)(m0 + wave * 16 + lr) * Kd + kt + lc], &As[(wave * 16 + lr) * BK + lc]);
        gl_lds16(&A [(size_t)(m0 + (wave + 4) * 16 + lr) * Kd + kt + lc], &As[((wave + 4) * 16 + lr) * BK + lc]);
        gl_lds16(&Bw[(size_t)(n0 + wave * 16 + lr) * Kd + kt + lc], &Bs[(wave * 16 + lr) * BK + lc]);
        __syncthreads();

        bf16x8 aF[4], bF[2];
#pragma unroll
        for (int mf = 0; mf < 4; ++mf)
            aF[mf] = *reinterpret_cast<const bf16x8*>(&As[(wm + mf * 16 + rw) * BK + g * 8]);
#pragma unroll
        for (int nf = 0; nf < 2; ++nf)
            bF[nf] = *reinterpret_cast<const bf16x8*>(&Bs[(wn + nf * 16 + rw) * BK + g * 8]);
#pragma unroll
        for (int mf = 0; mf < 4; ++mf)
#pragma unroll
            for (int nf = 0; nf < 2; ++nf)
                acc[mf][nf] = __builtin_amdgcn_mfma_f32_16x16x32_bf16(aF[mf], bF[nf], acc[mf][nf], 0, 0, 0);
    }

#pragma unroll
    for (int mf = 0; mf < 4; ++mf)
#pragma unroll
        for (int nf = 0; nf < 2; ++nf)
#pragma unroll
            for (int r = 0; r < 4; ++r) {
                int m = m0 + wm + mf * 16 + g * 4 + r;
                int n = n0 + wn + nf * 16 + rw;
                outp[(size_t)m * Nd + n] = acc[mf][nf][r] + bias[n];
            }
}

// ---------------------------------------------------------------- attention
// Block: 4 waves x 32 q = 128 q rows. KVBLK=64, K/V double-buffered in LDS,
// XOR-swizzled (chunk ^= row&7), staged once per block via global_load_lds.
// NSPLIT=2: grid 1024, each block covers 1024 kv, writes partials.
template <int NSPLIT>
__global__ __launch_bounds__(256)
void attn_kernel(const u16* __restrict__ Q, const u16* __restrict__ Kp,
                 const u16* __restrict__ VT, u16* __restrict__ ctx,
                 float* __restrict__ Opart, float* __restrict__ Mpart,
                 float* __restrict__ Lpart) {
    int bh, qb, split;
    if (NSPLIT == 2) {
        const int wg = (blockIdx.x & 7) * 128 + (blockIdx.x >> 3);   // bijective, 1024%8==0
        bh = wg >> 5;
        split = wg & 1;
        qb = ((wg >> 1) & 15) * 128;
    } else {
        const int wg = (blockIdx.x & 7) * 64 + (blockIdx.x >> 3);
        bh = wg >> 4;
        split = 0;
        qb = (wg & 15) * 128;
    }
    const int wave = threadIdx.x >> 6;
    const int lane = threadIdx.x & 63;
    const int l31 = lane & 31;
    const int hi = lane >> 5;
    const int q0 = qb + wave * 32;
    constexpr int KVLEN = GS / NSPLIT;
    constexpr int NT2 = KVLEN / 64;          // steps of 64 kv
    const int kvbase = split * KVLEN;

    const u16* __restrict__ Qbh = Q  + (size_t)bh * GS * GD;
    const u16* __restrict__ Kbh = Kp + (size_t)bh * GS * GD;
    const u16* __restrict__ Vbh = VT + (size_t)bh * GD * GS;

    // LDS: K tile [64 kv][64 d], V tile [64 d][64 kv], both 8KB, double-buffered.
    // Chunk = 16B (8 u16); 8 chunks/row. Content: LDS(r,w) = G(r, w^(r&7)).
    __shared__ u16 sK[2][4096];
    __shared__ u16 sV[2][4096];

    // Q fragments: B-operand of S^T = K.Q^T. lane: col q=l31, k(d)=16s+8hi+j
    bf16x8 qf[4];
#pragma unroll
    for (int s = 0; s < 4; ++s)
        qf[s] = *reinterpret_cast<const bf16x8*>(
            Qbh + (size_t)(q0 + l31) * GD + hi * 8 + 16 * s);

    f32x16 O0 = {}, O1 = {};
    float m = -1e30f, lsum = 0.f;
    const float SC = 0.125f * 1.44269504088896f;   // D^-1/2 * log2(e)

    // stage one 64-kv tile into buffer b: 4 gl_lds16 calls per wave
    auto stage = [&](int b, int kv0) {
#pragma unroll
        for (int j = 0; j < 2; ++j) {
            int c = (wave * 2 + j) * 64 + lane;      // chunk index in [0,512)
            int r = c >> 3, w = c & 7;
            gl_lds16(Kbh + (size_t)(kv0 + r) * GD + (w ^ (r & 7)) * 8,
                     &sK[b][c * 8]);
            gl_lds16(Vbh + (size_t)r * GS + kv0 + (w ^ (r & 7)) * 8,
                     &sV[b][c * 8]);
        }
    };

    // swizzled ds_read address (u16 index) for row r, chunk u
    auto swz = [&](int r, int u) { return r * 64 + ((u ^ (r & 7)) * 8); };

    stage(0, kvbase);
    __syncthreads();

    int buf = 0;
#pragma unroll 1
    for (int t = 0; t < NT2; ++t) {
        if (t + 1 < NT2) stage(buf ^ 1, kvbase + (t + 1) * 64);

        // ---- K fragments + QK^T (two independent 4-MFMA chains)
        f32x16 sa = {}, sb = {};
        {
            bf16x8 ka[4], kb[4];
#pragma unroll
            for (int s = 0; s < 4; ++s) {
                ka[s] = *reinterpret_cast<const bf16x8*>(&sK[buf][swz(l31,      2 * s + hi)]);
                kb[s] = *reinterpret_cast<const bf16x8*>(&sK[buf][swz(l31 + 32, 2 * s + hi)]);
            }
            __builtin_amdgcn_s_setprio(1);
#pragma unroll
            for (int s = 0; s < 4; ++s) {
                sa = __builtin_amdgcn_mfma_f32_32x32x16_bf16(ka[s], qf[s], sa, 0, 0, 0);
                sb = __builtin_amdgcn_mfma_f32_32x32x16_bf16(kb[s], qf[s], sb, 0, 0, 0);
            }
            __builtin_amdgcn_s_setprio(0);
        }

        // ---- V fragments (latency hidden under softmax VALU)
        bf16x8 vf0[4], vf1[4];
#pragma unroll
        for (int s = 0; s < 4; ++s) {
            vf0[s] = *reinterpret_cast<const bf16x8*>(&sV[buf][swz(l31,      2 * s + hi)]);
            vf1[s] = *reinterpret_cast<const bf16x8*>(&sV[buf][swz(l31 + 32, 2 * s + hi)]);
        }

        // ---- online softmax over 32 scores/lane (q = l31; partner has other 32 kv)
        float t16[16];
#pragma unroll
        for (int r = 0; r < 16; ++r) t16[r] = fmaxf(sa[r], sb[r]);
#pragma unroll
        for (int r = 0; r < 8; ++r) t16[r] = fmaxf(t16[r], t16[r + 8]);
#pragma unroll
        for (int r = 0; r < 4; ++r) t16[r] = fmaxf(t16[r], t16[r + 4]);
        float mx = fmaxf(fmaxf(t16[0], t16[1]), fmaxf(t16[2], t16[3]));
        mx = fmaxf(mx, xchg32(mx));
        float mxs = mx * SC;
        if (__any(mxs > m + 8.f)) {       // T13 defer-max
            float mn = fmaxf(m, mxs);
            float alpha = __builtin_amdgcn_exp2f(m - mn);
            m = mn;
            lsum *= alpha;
#pragma unroll
            for (int r = 0; r < 16; ++r) { O0[r] *= alpha; O1[r] *= alpha; }
        }
        float pa[16], pb[16];
#pragma unroll
        for (int r = 0; r < 16; ++r) {
            pa[r] = __builtin_amdgcn_exp2f(fmaf(sa[r], SC, -m));
            pb[r] = __builtin_amdgcn_exp2f(fmaf(sb[r], SC, -m));
        }
        float s16[16];
#pragma unroll
        for (int r = 0; r < 16; ++r) s16[r] = pa[r] + pb[r];
#pragma unroll
        for (int r = 0; r < 8; ++r) s16[r] += s16[r + 8];
#pragma unroll
        for (int r = 0; r < 4; ++r) s16[r] += s16[r + 4];
        float rs = (s16[0] + s16[1]) + (s16[2] + s16[3]);
        rs += xchg32(rs);
        lsum += rs;

        // ---- pack P -> PV B-fragments (verified R2 sequence, per 32-kv subtile)
        u32 wa[8], wb[8];
#pragma unroll
        for (int i = 0; i < 8; ++i) {
            wa[i] = cvtpk(pa[2 * i], pa[2 * i + 1]);
            wb[i] = cvtpk(pb[2 * i], pb[2 * i + 1]);
        }
        plswap(wa[0], wa[2]); plswap(wa[1], wa[3]);
        plswap(wa[4], wa[6]); plswap(wa[5], wa[7]);
        plswap(wb[0], wb[2]); plswap(wb[1], wb[3]);
        plswap(wb[4], wb[6]); plswap(wb[5], wb[7]);
        u32x4 a0 = {wa[0], wa[1], wa[2], wa[3]};
        u32x4 a1 = {wa[4], wa[5], wa[6], wa[7]};
        u32x4 b0 = {wb[0], wb[1], wb[2], wb[3]};
        u32x4 b1 = {wb[4], wb[5], wb[6], wb[7]};
        bf16x8 pva0 = __builtin_bit_cast(bf16x8, a0);
        bf16x8 pva1 = __builtin_bit_cast(bf16x8, a1);
        bf16x8 pvb0 = __builtin_bit_cast(bf16x8, b0);
        bf16x8 pvb1 = __builtin_bit_cast(bf16x8, b1);

        // ---- O^T += V^T . P^T   (vf slice s: kv chunk 2s+hi; subtile b = slices 2,3)
        __builtin_amdgcn_s_setprio(1);
        O0 = __builtin_amdgcn_mfma_f32_32x32x16_bf16(vf0[0], pva0, O0, 0, 0, 0);
        O0 = __builtin_amdgcn_mfma_f32_32x32x16_bf16(vf0[1], pva1, O0, 0, 0, 0);
        O0 = __builtin_amdgcn_mfma_f32_32x32x16_bf16(vf0[2], pvb0, O0, 0, 0, 0);
        O0 = __builtin_amdgcn_mfma_f32_32x32x16_bf16(vf0[3], pvb1, O0, 0, 0, 0);
        O1 = __builtin_amdgcn_mfma_f32_32x32x16_bf16(vf1[0], pva0, O1, 0, 0, 0);
        O1 = __builtin_amdgcn_mfma_f32_32x32x16_bf16(vf1[1], pva1, O1, 0, 0, 0);
        O1 = __builtin_amdgcn_mfma_f32_32x32x16_bf16(vf1[2], pvb0, O1, 0, 0, 0);
        O1 = __builtin_amdgcn_mfma_f32_32x32x16_bf16(vf1[3], pvb1, O1, 0, 0, 0);
        __builtin_amdgcn_s_setprio(0);

        __syncthreads();    // drains stage vmcnt + all waves' ds_reads of buf
        buf ^= 1;
    }

    if (NSPLIT == 2) {
        const int wt = bh * 64 + (q0 >> 5);
        const size_t base = ((size_t)wt * 2 + split) * PSTRIDE;
#pragma unroll
        for (int r = 0; r < 16; ++r) {
            int d = (r & 3) + 8 * (r >> 2) + 4 * hi;
            Opart[base + (size_t)d * 32 + l31]        = O0[r];
            Opart[base + (size_t)(d + 32) * 32 + l31] = O1[r];
        }
        if (hi == 0) {
            Mpart[(wt * 2 + split) * 32 + l31] = m;
            Lpart[(wt * 2 + split) * 32 + l31] = lsum;
        }
    } else {
        const int bb = bh >> 4, h = bh & 15;
        const float inv = 1.0f / lsum;
        u16* crow = ctx + ((size_t)(bb * GS + q0 + l31)) * GE + h * 64;
#pragma unroll
        for (int g2 = 0; g2 < 4; ++g2) {
            ushort4 st0, st1;
            st0.x = f2bf(O0[4 * g2 + 0] * inv); st0.y = f2bf(O0[4 * g2 + 1] * inv);
            st0.z = f2bf(O0[4 * g2 + 2] * inv); st0.w = f2bf(O0[4 * g2 + 3] * inv);
            st1.x = f2bf(O1[4 * g2 + 0] * inv); st1.y = f2bf(O1[4 * g2 + 1] * inv);
            st1.z = f2bf(O1[4 * g2 + 2] * inv); st1.w = f2bf(O1[4 * g2 + 3] * inv);
            *reinterpret_cast<ushort4*>(crow + 8 * g2 + 4 * hi)      = st0;
            *reinterpret_cast<ushort4*>(crow + 32 + 8 * g2 + 4 * hi) = st1;
        }
    }
}

// ---------------------------------------------------------------- combine
__global__ __launch_bounds__(256)
void combine_kernel(const float* __restrict__ Opart, const float* __restrict__ Mpart,
                    const float* __restrict__ Lpart, u16* __restrict__ ctx) {
    const int wt = blockIdx.x;
    const int bh = wt >> 6, bb = bh >> 4, h = bh & 15;
    const int q0 = (wt & 63) * 32;
    const int q = threadIdx.x & 31, db = threadIdx.x >> 5;
    const size_t b0 = (size_t)wt * 2 * PSTRIDE, b1 = b0 + PSTRIDE;

    float m0 = Mpart[(wt * 2 + 0) * 32 + q], m1 = Mpart[(wt * 2 + 1) * 32 + q];
    float l0 = Lpart[(wt * 2 + 0) * 32 + q], l1 = Lpart[(wt * 2 + 1) * 32 + q];
    float M = fmaxf(m0, m1);
    float c0 = exp2f(m0 - M), c1 = exp2f(m1 - M);
    float inv = 1.f / (c0 * l0 + c1 * l1);
    c0 *= inv; c1 *= inv;

    u16* crow = ctx + ((size_t)(bb * GS + q0 + q)) * GE + h * 64 + db * 8;
    ushort4 s0, s1;
    float o[8];
#pragma unroll
    for (int i = 0; i < 8; ++i) {
        int d = db * 8 + i;
        o[i] = c0 * Opart[b0 + (size_t)d * 32 + q] + c1 * Opart[b1 + (size_t)d * 32 + q];
    }
    s0.x = f2bf(o[0]); s0.y = f2bf(o[1]); s0.z = f2bf(o[2]); s0.w = f2bf(o[3]);
    s1.x = f2bf(o[4]); s1.y = f2bf(o[5]); s1.z = f2bf(o[6]); s1.w = f2bf(o[7]);
    *reinterpret_cast<ushort4*>(crow)     = s0;
    *reinterpret_cast<ushort4*>(crow + 4) = s1;
}

// ---------------------------------------------------------------- launcher
extern "C" void kernel_launch(void* const* d_in, const int* in_sizes, int n_in,
                              void* d_out, int out_size, void* d_ws, size_t ws_size,
                              hipStream_t stream) {
    (void)in_sizes; (void)n_in; (void)out_size;

    const float* x  = (const float*)d_in[0];
    const float* Wq = (const float*)d_in[1];
    const float* bq = (const float*)d_in[2];
    const float* Wk = (const float*)d_in[3];
    const float* bk = (const float*)d_in[4];
    const float* Wv = (const float*)d_in[5];
    const float* bv = (const float*)d_in[6];
    const float* Wo = (const float*)d_in[7];
    const float* bo = (const float*)d_in[8];
    float* out = (float*)d_out;

    char* ws = (char*)d_ws;
    u16* xb  = (u16*)(ws);                    // 8 MB  [4096,1024]
    u16* wqb = (u16*)(ws + (8ll  << 20));
    u16* wkb = (u16*)(ws + (10ll << 20));
    u16* wvb = (u16*)(ws + (12ll << 20));
    u16* wob = (u16*)(ws + (14ll << 20));
    u16* Qb  = (u16*)(ws + (16ll << 20));     // [B,H,S,D]
    u16* Kb  = (u16*)(ws + (24ll << 20));     // [B,H,S,D]
    u16* VTb = (u16*)(ws + (32ll << 20));     // [B,H,D,S]
    u16* ctx = (u16*)(ws + (40ll << 20));     // [B,S,E]
    float* Opart = (float*)(ws + (48ll << 20));   // 32 MB
    float* Mpart = (float*)(ws + (80ll << 20));
    float* Lpart = (float*)(ws + (80ll << 20) + (512ll << 10));
    const bool split2 = ws_size >= (81ll << 20);

    cvt_kernel<<<2048, 256, 0, stream>>>(x, xb, GM * GE);
    cvtw_kernel<<<dim3(512, 4), 256, 0, stream>>>(Wq, Wk, Wv, Wo, wqb, wkb, wvb, wob);

    qkv_gemm<<<dim3(GE / 64, GM / 128, 3), 256, 0, stream>>>(
        xb, wqb, wkb, wvb, bq, bk, bv, Qb, Kb, VTb);

    if (split2) {
        attn_kernel<2><<<dim3(1024), 256, 0, stream>>>(Qb, Kb, VTb, ctx, Opart, Mpart, Lpart);
        combine_kernel<<<dim3(2048), 256, 0, stream>>>(Opart, Mpart, Lpart, ctx);
    } else {
        attn_kernel<1><<<dim3(512), 256, 0, stream>>>(Qb, Kb, VTb, ctx, Opart, Mpart, Lpart);
    }

    out_gemm<<<dim3(GE / 64, GM / 128), 256, 0, stream>>>(ctx, wob, bo, out);
}

// Round 7
// 142.444 us; speedup vs baseline: 2.4594x; 1.1174x over previous
//
#include <hip/hip_runtime.h>

// ---------------------------------------------------------------------------
// Fused MHA block for MI355X (gfx950).
// B=2, S=2048, E=1024, H=16, D=64. f32 in/out, bf16 MFMA internally.
//
//   cvt:      x, {Wq,Wk,Wv,Wo} f32 -> bf16 (ws)
//   qkv_gemm: 128x128 tile (m97 structure), grid.z=3: Q,K -> [B,H,S,D]; V -> [B,H,D,S]
//   attn:     swapped-operand flash attention, kv-split 2, KVBLK=64, LDS-staged K/V
//   combine:  merge 2 kv-splits -> ctx bf16 [B,S,E]
//   out_gemm: 128x128 tile, out = ctx@Wo^T+bo -> f32 d_out
//
// permlane32_swap: a' = {a_lo || b_lo}, b' = {a_hi || b_hi}   (verified R2)
// ---------------------------------------------------------------------------

using u16 = unsigned short;
using u32 = unsigned int;

typedef __bf16 bf16x8 __attribute__((ext_vector_type(8)));
typedef float  f32x4  __attribute__((ext_vector_type(4)));
typedef float  f32x16 __attribute__((ext_vector_type(16)));
typedef u32    u32x4  __attribute__((ext_vector_type(4)));

constexpr int GB = 2;
constexpr int GS = 2048;
constexpr int GH = 16;
constexpr int GD = 64;
constexpr int GE = 1024;
constexpr int GM = GB * GS;      // 4096 rows
constexpr int PSTRIDE = 2048;    // floats per (q-tile, split) partial: 32 q x 64 d

__device__ __forceinline__ u16 f2bf(float f) {
    u32 u = __float_as_uint(f);
    u += 0x7FFFu + ((u >> 16) & 1u);   // RTNE
    return (u16)(u >> 16);
}

__device__ __forceinline__ void plswap(u32& a, u32& b) {
#if __has_builtin(__builtin_amdgcn_permlane32_swap)
    auto r = __builtin_amdgcn_permlane32_swap(a, b, false, false);
    a = r[0]; b = r[1];
#else
    asm volatile("v_permlane32_swap_b32 %0, %1" : "+v"(a), "+v"(b));
#endif
}

__device__ __forceinline__ float xchg32(float v) {
    u32 a = __float_as_uint(v), b = a;
    plswap(a, b);
    return __uint_as_float((threadIdx.x & 32) ? a : b);
}

__device__ __forceinline__ u32 cvtpk(float lo, float hi) {
    u32 d;
    asm("v_cvt_pk_bf16_f32 %0, %1, %2" : "=v"(d) : "v"(lo), "v"(hi));
    return d;
}

// async global -> LDS, 16 B per lane (linear dest: base + lane*16)
__device__ __forceinline__ void gl_lds16(const u16* g, u16* l) {
#if __has_builtin(__builtin_amdgcn_global_load_lds)
    __builtin_amdgcn_global_load_lds(
        (const __attribute__((address_space(1))) void*)g,
        (__attribute__((address_space(3))) void*)l, 16, 0, 0);
#else
    *reinterpret_cast<uint4*>(l) = *reinterpret_cast<const uint4*>(g);
#endif
}

// ---------------------------------------------------------------- cvt kernels
__global__ void cvt_kernel(const float* __restrict__ in, u16* __restrict__ out, int n) {
    int idx = blockIdx.x * blockDim.x + threadIdx.x;
    int stride = gridDim.x * blockDim.x;
    for (int i = idx * 4; i < n; i += stride * 4) {
        float4 f = *reinterpret_cast<const float4*>(in + i);
        ushort4 o;
        o.x = f2bf(f.x); o.y = f2bf(f.y); o.z = f2bf(f.z); o.w = f2bf(f.w);
        *reinterpret_cast<ushort4*>(out + i) = o;
    }
}

__global__ void cvtw_kernel(const float* __restrict__ w0, const float* __restrict__ w1,
                            const float* __restrict__ w2, const float* __restrict__ w3,
                            u16* __restrict__ o0, u16* __restrict__ o1,
                            u16* __restrict__ o2, u16* __restrict__ o3) {
    const float* in = blockIdx.y == 0 ? w0 : blockIdx.y == 1 ? w1 : blockIdx.y == 2 ? w2 : w3;
    u16* out = blockIdx.y == 0 ? o0 : blockIdx.y == 1 ? o1 : blockIdx.y == 2 ? o2 : o3;
    int idx = blockIdx.x * blockDim.x + threadIdx.x;
    int stride = gridDim.x * blockDim.x;
    for (int i = idx * 4; i < GE * GE; i += stride * 4) {
        float4 f = *reinterpret_cast<const float4*>(in + i);
        ushort4 o;
        o.x = f2bf(f.x); o.y = f2bf(f.y); o.z = f2bf(f.z); o.w = f2bf(f.w);
        *reinterpret_cast<ushort4*>(out + i) = o;
    }
}

// ---------------------------------------------------------------- GEMM 128x128
// m97 structure: BK=32, 4 waves each 64x64 out (4x4 of 16x16 MFMA),
// global_load_lds staging (2 calls/wave/operand), linear LDS.
// C[m,n] = sum_k A[m,k]*W[n,k] + bias[n].

// QKV fused: grid (8, 32, 3). z=0 -> Q [B,H,S,D], z=1 -> K, z=2 -> V^T [B,H,D,S].
__global__ __launch_bounds__(256)
void qkv_gemm(const u16* __restrict__ A,
              const u16* __restrict__ wq, const u16* __restrict__ wk, const u16* __restrict__ wv,
              const float* __restrict__ bq, const float* __restrict__ bk, const float* __restrict__ bv,
              u16* __restrict__ Qb, u16* __restrict__ Kb, u16* __restrict__ VTb) {
    constexpr int Kd = GE;
    __shared__ u16 As[128 * 32];
    __shared__ u16 Bs[128 * 32];

    const int z = blockIdx.z;
    const u16* __restrict__ Bw = z == 0 ? wq : z == 1 ? wk : wv;
    const float* __restrict__ bias = z == 0 ? bq : z == 1 ? bk : bv;
    u16* __restrict__ outp = z == 0 ? Qb : z == 1 ? Kb : VTb;

    const int tid = threadIdx.x;
    const int m0 = blockIdx.y * 128;
    const int n0 = blockIdx.x * 128;
    const int wave = tid >> 6, lane = tid & 63;
    const int wm = (wave >> 1) * 64, wn = (wave & 1) * 64;
    const int g = lane >> 4, rw = lane & 15;

    f32x4 acc[4][4] = {};

    for (int kt = 0; kt < Kd; kt += 32) {
        __syncthreads();
#pragma unroll
        for (int j = 0; j < 2; ++j) {
            int c = wave * 128 + j * 64 + lane;      // chunk in [0,512)
            int r = c >> 2, u = (c & 3) * 8;
            gl_lds16(&A [(size_t)(m0 + r) * Kd + kt + u], &As[c * 8]);
            gl_lds16(&Bw[(size_t)(n0 + r) * Kd + kt + u], &Bs[c * 8]);
        }
        __syncthreads();

        bf16x8 aF[4], bF[4];
#pragma unroll
        for (int mf = 0; mf < 4; ++mf)
            aF[mf] = *reinterpret_cast<const bf16x8*>(&As[(wm + mf * 16 + rw) * 32 + g * 8]);
#pragma unroll
        for (int nf = 0; nf < 4; ++nf)
            bF[nf] = *reinterpret_cast<const bf16x8*>(&Bs[(wn + nf * 16 + rw) * 32 + g * 8]);
#pragma unroll
        for (int mf = 0; mf < 4; ++mf)
#pragma unroll
            for (int nf = 0; nf < 4; ++nf)
                acc[mf][nf] = __builtin_amdgcn_mfma_f32_16x16x32_bf16(aF[mf], bF[nf], acc[mf][nf], 0, 0, 0);
    }

#pragma unroll
    for (int mf = 0; mf < 4; ++mf)
#pragma unroll
        for (int nf = 0; nf < 4; ++nf)
#pragma unroll
            for (int r = 0; r < 4; ++r) {
                int m = m0 + wm + mf * 16 + g * 4 + r;
                int n = n0 + wn + nf * 16 + rw;
                u16 hv = f2bf(acc[mf][nf][r] + bias[n]);
                int b = m >> 11, s = m & (GS - 1);
                int h = n >> 6, d = n & 63;
                if (z == 2)
                    outp[(((size_t)(b * GH + h)) * GD + d) * GS + s] = hv;
                else
                    outp[(((size_t)(b * GH + h)) * GS + s) * GD + d] = hv;
            }
}

// out-projection: f32 out [m, n]. grid (8, 32).
__global__ __launch_bounds__(256)
void out_gemm(const u16* __restrict__ A, const u16* __restrict__ Bw,
              const float* __restrict__ bias, float* __restrict__ outp) {
    constexpr int Kd = GE, Nd = GE;
    __shared__ u16 As[128 * 32];
    __shared__ u16 Bs[128 * 32];

    const int tid = threadIdx.x;
    const int m0 = blockIdx.y * 128;
    const int n0 = blockIdx.x * 128;
    const int wave = tid >> 6, lane = tid & 63;
    const int wm = (wave >> 1) * 64, wn = (wave & 1) * 64;
    const int g = lane >> 4, rw = lane & 15;

    f32x4 acc[4][4] = {};

    for (int kt = 0; kt < Kd; kt += 32) {
        __syncthreads();
#pragma unroll
        for (int j = 0; j < 2; ++j) {
            int c = wave * 128 + j * 64 + lane;
            int r = c >> 2, u = (c & 3) * 8;
            gl_lds16(&A [(size_t)(m0 + r) * Kd + kt + u], &As[c * 8]);
            gl_lds16(&Bw[(size_t)(n0 + r) * Kd + kt + u], &Bs[c * 8]);
        }
        __syncthreads();

        bf16x8 aF[4], bF[4];
#pragma unroll
        for (int mf = 0; mf < 4; ++mf)
            aF[mf] = *reinterpret_cast<const bf16x8*>(&As[(wm + mf * 16 + rw) * 32 + g * 8]);
#pragma unroll
        for (int nf = 0; nf < 4; ++nf)
            bF[nf] = *reinterpret_cast<const bf16x8*>(&Bs[(wn + nf * 16 + rw) * 32 + g * 8]);
#pragma unroll
        for (int mf = 0; mf < 4; ++mf)
#pragma unroll
            for (int nf = 0; nf < 4; ++nf)
                acc[mf][nf] = __builtin_amdgcn_mfma_f32_16x16x32_bf16(aF[mf], bF[nf], acc[mf][nf], 0, 0, 0);
    }

#pragma unroll
    for (int mf = 0; mf < 4; ++mf)
#pragma unroll
        for (int nf = 0; nf < 4; ++nf)
#pragma unroll
            for (int r = 0; r < 4; ++r) {
                int m = m0 + wm + mf * 16 + g * 4 + r;
                int n = n0 + wn + nf * 16 + rw;
                outp[(size_t)m * Nd + n] = acc[mf][nf][r] + bias[n];
            }
}

// ---------------------------------------------------------------- attention
// Block: 4 waves x 32 q = 128 q rows. KVBLK=64, K/V double-buffered in LDS,
// chunk^=(row&7) swizzle, staged via global_load_lds (frozen R5 structure).
// R6 trims: max3-fusable max tree; lsum cross-half exchange deferred to end.
template <int NSPLIT>
__global__ __launch_bounds__(256)
void attn_kernel(const u16* __restrict__ Q, const u16* __restrict__ Kp,
                 const u16* __restrict__ VT, u16* __restrict__ ctx,
                 float* __restrict__ Opart, float* __restrict__ Mpart,
                 float* __restrict__ Lpart) {
    int bh, qb, split;
    if (NSPLIT == 2) {
        const int wg = (blockIdx.x & 7) * 128 + (blockIdx.x >> 3);   // bijective, 1024%8==0
        bh = wg >> 5;
        split = wg & 1;
        qb = ((wg >> 1) & 15) * 128;
    } else {
        const int wg = (blockIdx.x & 7) * 64 + (blockIdx.x >> 3);
        bh = wg >> 4;
        split = 0;
        qb = (wg & 15) * 128;
    }
    const int wave = threadIdx.x >> 6;
    const int lane = threadIdx.x & 63;
    const int l31 = lane & 31;
    const int hi = lane >> 5;
    const int q0 = qb + wave * 32;
    constexpr int KVLEN = GS / NSPLIT;
    constexpr int NT2 = KVLEN / 64;
    const int kvbase = split * KVLEN;

    const u16* __restrict__ Qbh = Q  + (size_t)bh * GS * GD;
    const u16* __restrict__ Kbh = Kp + (size_t)bh * GS * GD;
    const u16* __restrict__ Vbh = VT + (size_t)bh * GD * GS;

    __shared__ u16 sK[2][4096];
    __shared__ u16 sV[2][4096];

    bf16x8 qf[4];
#pragma unroll
    for (int s = 0; s < 4; ++s)
        qf[s] = *reinterpret_cast<const bf16x8*>(
            Qbh + (size_t)(q0 + l31) * GD + hi * 8 + 16 * s);

    f32x16 O0 = {}, O1 = {};
    float m = -1e30f, lsum = 0.f;
    const float SC = 0.125f * 1.44269504088896f;   // D^-1/2 * log2(e)

    auto stage = [&](int b, int kv0) {
#pragma unroll
        for (int j = 0; j < 2; ++j) {
            int c = (wave * 2 + j) * 64 + lane;
            int r = c >> 3, w = c & 7;
            gl_lds16(Kbh + (size_t)(kv0 + r) * GD + (w ^ (r & 7)) * 8,
                     &sK[b][c * 8]);
            gl_lds16(Vbh + (size_t)r * GS + kv0 + (w ^ (r & 7)) * 8,
                     &sV[b][c * 8]);
        }
    };

    auto swz = [&](int r, int u) { return r * 64 + ((u ^ (r & 7)) * 8); };

    stage(0, kvbase);
    __syncthreads();

    int buf = 0;
#pragma unroll 1
    for (int t = 0; t < NT2; ++t) {
        if (t + 1 < NT2) stage(buf ^ 1, kvbase + (t + 1) * 64);

        f32x16 sa = {}, sb = {};
        {
            bf16x8 ka[4], kb[4];
#pragma unroll
            for (int s = 0; s < 4; ++s) {
                ka[s] = *reinterpret_cast<const bf16x8*>(&sK[buf][swz(l31,      2 * s + hi)]);
                kb[s] = *reinterpret_cast<const bf16x8*>(&sK[buf][swz(l31 + 32, 2 * s + hi)]);
            }
            __builtin_amdgcn_s_setprio(1);
#pragma unroll
            for (int s = 0; s < 4; ++s) {
                sa = __builtin_amdgcn_mfma_f32_32x32x16_bf16(ka[s], qf[s], sa, 0, 0, 0);
                sb = __builtin_amdgcn_mfma_f32_32x32x16_bf16(kb[s], qf[s], sb, 0, 0, 0);
            }
            __builtin_amdgcn_s_setprio(0);
        }

        bf16x8 vf0[4], vf1[4];
#pragma unroll
        for (int s = 0; s < 4; ++s) {
            vf0[s] = *reinterpret_cast<const bf16x8*>(&sV[buf][swz(l31,      2 * s + hi)]);
            vf1[s] = *reinterpret_cast<const bf16x8*>(&sV[buf][swz(l31 + 32, 2 * s + hi)]);
        }

        // ---- online softmax (max tree shaped for v_max3 fusion)
        float t16[16];
#pragma unroll
        for (int r = 0; r < 16; ++r) t16[r] = fmaxf(sa[r], sb[r]);
        float u0 = fmaxf(fmaxf(t16[0],  t16[1]),  t16[2]);
        float u1 = fmaxf(fmaxf(t16[3],  t16[4]),  t16[5]);
        float u2 = fmaxf(fmaxf(t16[6],  t16[7]),  t16[8]);
        float u3 = fmaxf(fmaxf(t16[9],  t16[10]), t16[11]);
        float u4 = fmaxf(fmaxf(t16[12], t16[13]), t16[14]);
        float w0 = fmaxf(fmaxf(u0, u1), u2);
        float w1 = fmaxf(fmaxf(u3, u4), t16[15]);
        float mx = fmaxf(w0, w1);
        mx = fmaxf(mx, xchg32(mx));
        float mxs = mx * SC;
        if (__any(mxs > m + 8.f)) {       // T13 defer-max
            float mn = fmaxf(m, mxs);
            float alpha = __builtin_amdgcn_exp2f(m - mn);
            m = mn;
            lsum *= alpha;
#pragma unroll
            for (int r = 0; r < 16; ++r) { O0[r] *= alpha; O1[r] *= alpha; }
        }
        float pa[16], pb[16];
#pragma unroll
        for (int r = 0; r < 16; ++r) {
            pa[r] = __builtin_amdgcn_exp2f(fmaf(sa[r], SC, -m));
            pb[r] = __builtin_amdgcn_exp2f(fmaf(sb[r], SC, -m));
        }
        float s16[16];
#pragma unroll
        for (int r = 0; r < 16; ++r) s16[r] = pa[r] + pb[r];
#pragma unroll
        for (int r = 0; r < 8; ++r) s16[r] += s16[r + 8];
#pragma unroll
        for (int r = 0; r < 4; ++r) s16[r] += s16[r + 4];
        lsum += (s16[0] + s16[1]) + (s16[2] + s16[3]);   // own-half only; xchg deferred

        // ---- pack P -> PV B-fragments
        u32 wa[8], wb[8];
#pragma unroll
        for (int i = 0; i < 8; ++i) {
            wa[i] = cvtpk(pa[2 * i], pa[2 * i + 1]);
            wb[i] = cvtpk(pb[2 * i], pb[2 * i + 1]);
        }
        plswap(wa[0], wa[2]); plswap(wa[1], wa[3]);
        plswap(wa[4], wa[6]); plswap(wa[5], wa[7]);
        plswap(wb[0], wb[2]); plswap(wb[1], wb[3]);
        plswap(wb[4], wb[6]); plswap(wb[5], wb[7]);
        u32x4 a0 = {wa[0], wa[1], wa[2], wa[3]};
        u32x4 a1 = {wa[4], wa[5], wa[6], wa[7]};
        u32x4 b0 = {wb[0], wb[1], wb[2], wb[3]};
        u32x4 b1 = {wb[4], wb[5], wb[6], wb[7]};
        bf16x8 pva0 = __builtin_bit_cast(bf16x8, a0);
        bf16x8 pva1 = __builtin_bit_cast(bf16x8, a1);
        bf16x8 pvb0 = __builtin_bit_cast(bf16x8, b0);
        bf16x8 pvb1 = __builtin_bit_cast(bf16x8, b1);

        __builtin_amdgcn_s_setprio(1);
        O0 = __builtin_amdgcn_mfma_f32_32x32x16_bf16(vf0[0], pva0, O0, 0, 0, 0);
        O0 = __builtin_amdgcn_mfma_f32_32x32x16_bf16(vf0[1], pva1, O0, 0, 0, 0);
        O0 = __builtin_amdgcn_mfma_f32_32x32x16_bf16(vf0[2], pvb0, O0, 0, 0, 0);
        O0 = __builtin_amdgcn_mfma_f32_32x32x16_bf16(vf0[3], pvb1, O0, 0, 0, 0);
        O1 = __builtin_amdgcn_mfma_f32_32x32x16_bf16(vf1[0], pva0, O1, 0, 0, 0);
        O1 = __builtin_amdgcn_mfma_f32_32x32x16_bf16(vf1[1], pva1, O1, 0, 0, 0);
        O1 = __builtin_amdgcn_mfma_f32_32x32x16_bf16(vf1[2], pvb0, O1, 0, 0, 0);
        O1 = __builtin_amdgcn_mfma_f32_32x32x16_bf16(vf1[3], pvb1, O1, 0, 0, 0);
        __builtin_amdgcn_s_setprio(0);

        __syncthreads();
        buf ^= 1;
    }

    lsum += xchg32(lsum);      // deferred cross-half combine (alphas identical)

    if (NSPLIT == 2) {
        const int wt = bh * 64 + (q0 >> 5);
        const size_t base = ((size_t)wt * 2 + split) * PSTRIDE;
#pragma unroll
        for (int r = 0; r < 16; ++r) {
            int d = (r & 3) + 8 * (r >> 2) + 4 * hi;
            Opart[base + (size_t)d * 32 + l31]        = O0[r];
            Opart[base + (size_t)(d + 32) * 32 + l31] = O1[r];
        }
        if (hi == 0) {
            Mpart[(wt * 2 + split) * 32 + l31] = m;
            Lpart[(wt * 2 + split) * 32 + l31] = lsum;
        }
    } else {
        const int bb = bh >> 4, h = bh & 15;
        const float inv = 1.0f / lsum;
        u16* crow = ctx + ((size_t)(bb * GS + q0 + l31)) * GE + h * 64;
#pragma unroll
        for (int g2 = 0; g2 < 4; ++g2) {
            ushort4 st0, st1;
            st0.x = f2bf(O0[4 * g2 + 0] * inv); st0.y = f2bf(O0[4 * g2 + 1] * inv);
            st0.z = f2bf(O0[4 * g2 + 2] * inv); st0.w = f2bf(O0[4 * g2 + 3] * inv);
            st1.x = f2bf(O1[4 * g2 + 0] * inv); st1.y = f2bf(O1[4 * g2 + 1] * inv);
            st1.z = f2bf(O1[4 * g2 + 2] * inv); st1.w = f2bf(O1[4 * g2 + 3] * inv);
            *reinterpret_cast<ushort4*>(crow + 8 * g2 + 4 * hi)      = st0;
            *reinterpret_cast<ushort4*>(crow + 32 + 8 * g2 + 4 * hi) = st1;
        }
    }
}

// ---------------------------------------------------------------- combine
__global__ __launch_bounds__(256)
void combine_kernel(const float* __restrict__ Opart, const float* __restrict__ Mpart,
                    const float* __restrict__ Lpart, u16* __restrict__ ctx) {
    const int wt = blockIdx.x;
    const int bh = wt >> 6, bb = bh >> 4, h = bh & 15;
    const int q0 = (wt & 63) * 32;
    const int q = threadIdx.x & 31, db = threadIdx.x >> 5;
    const size_t b0 = (size_t)wt * 2 * PSTRIDE, b1 = b0 + PSTRIDE;

    float m0 = Mpart[(wt * 2 + 0) * 32 + q], m1 = Mpart[(wt * 2 + 1) * 32 + q];
    float l0 = Lpart[(wt * 2 + 0) * 32 + q], l1 = Lpart[(wt * 2 + 1) * 32 + q];
    float M = fmaxf(m0, m1);
    float c0 = exp2f(m0 - M), c1 = exp2f(m1 - M);
    float inv = 1.f / (c0 * l0 + c1 * l1);
    c0 *= inv; c1 *= inv;

    u16* crow = ctx + ((size_t)(bb * GS + q0 + q)) * GE + h * 64 + db * 8;
    ushort4 s0, s1;
    float o[8];
#pragma unroll
    for (int i = 0; i < 8; ++i) {
        int d = db * 8 + i;
        o[i] = c0 * Opart[b0 + (size_t)d * 32 + q] + c1 * Opart[b1 + (size_t)d * 32 + q];
    }
    s0.x = f2bf(o[0]); s0.y = f2bf(o[1]); s0.z = f2bf(o[2]); s0.w = f2bf(o[3]);
    s1.x = f2bf(o[4]); s1.y = f2bf(o[5]); s1.z = f2bf(o[6]); s1.w = f2bf(o[7]);
    *reinterpret_cast<ushort4*>(crow)     = s0;
    *reinterpret_cast<ushort4*>(crow + 4) = s1;
}

// ---------------------------------------------------------------- launcher
extern "C" void kernel_launch(void* const* d_in, const int* in_sizes, int n_in,
                              void* d_out, int out_size, void* d_ws, size_t ws_size,
                              hipStream_t stream) {
    (void)in_sizes; (void)n_in; (void)out_size;

    const float* x  = (const float*)d_in[0];
    const float* Wq = (const float*)d_in[1];
    const float* bq = (const float*)d_in[2];
    const float* Wk = (const float*)d_in[3];
    const float* bk = (const float*)d_in[4];
    const float* Wv = (const float*)d_in[5];
    const float* bv = (const float*)d_in[6];
    const float* Wo = (const float*)d_in[7];
    const float* bo = (const float*)d_in[8];
    float* out = (float*)d_out;

    char* ws = (char*)d_ws;
    u16* xb  = (u16*)(ws);                    // 8 MB  [4096,1024]
    u16* wqb = (u16*)(ws + (8ll  << 20));
    u16* wkb = (u16*)(ws + (10ll << 20));
    u16* wvb = (u16*)(ws + (12ll << 20));
    u16* wob = (u16*)(ws + (14ll << 20));
    u16* Qb  = (u16*)(ws + (16ll << 20));     // [B,H,S,D]
    u16* Kb  = (u16*)(ws + (24ll << 20));     // [B,H,S,D]
    u16* VTb = (u16*)(ws + (32ll << 20));     // [B,H,D,S]
    u16* ctx = (u16*)(ws + (40ll << 20));     // [B,S,E]
    float* Opart = (float*)(ws + (48ll << 20));   // 32 MB
    float* Mpart = (float*)(ws + (80ll << 20));
    float* Lpart = (float*)(ws + (80ll << 20) + (512ll << 10));
    const bool split2 = ws_size >= (81ll << 20);

    cvt_kernel<<<2048, 256, 0, stream>>>(x, xb, GM * GE);
    cvtw_kernel<<<dim3(512, 4), 256, 0, stream>>>(Wq, Wk, Wv, Wo, wqb, wkb, wvb, wob);

    qkv_gemm<<<dim3(GE / 128, GM / 128, 3), 256, 0, stream>>>(
        xb, wqb, wkb, wvb, bq, bk, bv, Qb, Kb, VTb);

    if (split2) {
        attn_kernel<2><<<dim3(1024), 256, 0, stream>>>(Qb, Kb, VTb, ctx, Opart, Mpart, Lpart);
        combine_kernel<<<dim3(2048), 256, 0, stream>>>(Opart, Mpart, Lpart, ctx);
    } else {
        attn_kernel<1><<<dim3(512), 256, 0, stream>>>(Qb, Kb, VTb, ctx, Opart, Mpart, Lpart);
    }

    out_gemm<<<dim3(GE / 128, GM / 128), 256, 0, stream>>>(ctx, wob, bo, out);
}

// Round 8
// 136.020 us; speedup vs baseline: 2.5756x; 1.0472x over previous
//
#include <hip/hip_runtime.h>

// ---------------------------------------------------------------------------
// Fused MHA block for MI355X (gfx950).
// B=2, S=2048, E=1024, H=16, D=64. f32 in/out, bf16 MFMA internally.
//
//   cvt:      x, {Wq,Wk,Wv,Wo} f32 -> bf16 (ws)
//   qkv_gemm: 128x128 tile (m97 structure), grid.z=3: Q,K -> [B,H,S,D]; V -> [B,H,D,S]
//   attn:     swapped-operand flash attention, kv-split 2, KVBLK=64, LDS-staged K/V
//             R7: all staging/ds_read addresses hoisted out of the K-loop
//   combine:  merge 2 kv-splits -> ctx bf16 [B,S,E]
//   out_gemm: 128x128 tile, out = ctx@Wo^T+bo -> f32 d_out
//
// permlane32_swap: a' = {a_lo || b_lo}, b' = {a_hi || b_hi}   (verified R2)
// ---------------------------------------------------------------------------

using u16 = unsigned short;
using u32 = unsigned int;

typedef __bf16 bf16x8 __attribute__((ext_vector_type(8)));
typedef float  f32x4  __attribute__((ext_vector_type(4)));
typedef float  f32x16 __attribute__((ext_vector_type(16)));
typedef u32    u32x4  __attribute__((ext_vector_type(4)));

constexpr int GB = 2;
constexpr int GS = 2048;
constexpr int GH = 16;
constexpr int GD = 64;
constexpr int GE = 1024;
constexpr int GM = GB * GS;      // 4096 rows
constexpr int PSTRIDE = 2048;    // floats per (q-tile, split) partial: 32 q x 64 d

__device__ __forceinline__ u16 f2bf(float f) {
    u32 u = __float_as_uint(f);
    u += 0x7FFFu + ((u >> 16) & 1u);   // RTNE
    return (u16)(u >> 16);
}

__device__ __forceinline__ void plswap(u32& a, u32& b) {
#if __has_builtin(__builtin_amdgcn_permlane32_swap)
    auto r = __builtin_amdgcn_permlane32_swap(a, b, false, false);
    a = r[0]; b = r[1];
#else
    asm volatile("v_permlane32_swap_b32 %0, %1" : "+v"(a), "+v"(b));
#endif
}

__device__ __forceinline__ float xchg32(float v) {
    u32 a = __float_as_uint(v), b = a;
    plswap(a, b);
    return __uint_as_float((threadIdx.x & 32) ? a : b);
}

__device__ __forceinline__ u32 cvtpk(float lo, float hi) {
    u32 d;
    asm("v_cvt_pk_bf16_f32 %0, %1, %2" : "=v"(d) : "v"(lo), "v"(hi));
    return d;
}

// async global -> LDS, 16 B per lane (linear dest: base + lane*16)
__device__ __forceinline__ void gl_lds16(const u16* g, u16* l) {
#if __has_builtin(__builtin_amdgcn_global_load_lds)
    __builtin_amdgcn_global_load_lds(
        (const __attribute__((address_space(1))) void*)g,
        (__attribute__((address_space(3))) void*)l, 16, 0, 0);
#else
    *reinterpret_cast<uint4*>(l) = *reinterpret_cast<const uint4*>(g);
#endif
}

// ---------------------------------------------------------------- cvt kernels
__global__ void cvt_kernel(const float* __restrict__ in, u16* __restrict__ out, int n) {
    int idx = blockIdx.x * blockDim.x + threadIdx.x;
    int stride = gridDim.x * blockDim.x;
    for (int i = idx * 4; i < n; i += stride * 4) {
        float4 f = *reinterpret_cast<const float4*>(in + i);
        ushort4 o;
        o.x = f2bf(f.x); o.y = f2bf(f.y); o.z = f2bf(f.z); o.w = f2bf(f.w);
        *reinterpret_cast<ushort4*>(out + i) = o;
    }
}

__global__ void cvtw_kernel(const float* __restrict__ w0, const float* __restrict__ w1,
                            const float* __restrict__ w2, const float* __restrict__ w3,
                            u16* __restrict__ o0, u16* __restrict__ o1,
                            u16* __restrict__ o2, u16* __restrict__ o3) {
    const float* in = blockIdx.y == 0 ? w0 : blockIdx.y == 1 ? w1 : blockIdx.y == 2 ? w2 : w3;
    u16* out = blockIdx.y == 0 ? o0 : blockIdx.y == 1 ? o1 : blockIdx.y == 2 ? o2 : o3;
    int idx = blockIdx.x * blockDim.x + threadIdx.x;
    int stride = gridDim.x * blockDim.x;
    for (int i = idx * 4; i < GE * GE; i += stride * 4) {
        float4 f = *reinterpret_cast<const float4*>(in + i);
        ushort4 o;
        o.x = f2bf(f.x); o.y = f2bf(f.y); o.z = f2bf(f.z); o.w = f2bf(f.w);
        *reinterpret_cast<ushort4*>(out + i) = o;
    }
}

// ---------------------------------------------------------------- GEMM 128x128
// (frozen from R6) m97 structure: BK=32, 4 waves each 64x64 out.
__global__ __launch_bounds__(256)
void qkv_gemm(const u16* __restrict__ A,
              const u16* __restrict__ wq, const u16* __restrict__ wk, const u16* __restrict__ wv,
              const float* __restrict__ bq, const float* __restrict__ bk, const float* __restrict__ bv,
              u16* __restrict__ Qb, u16* __restrict__ Kb, u16* __restrict__ VTb) {
    constexpr int Kd = GE;
    __shared__ u16 As[128 * 32];
    __shared__ u16 Bs[128 * 32];

    const int z = blockIdx.z;
    const u16* __restrict__ Bw = z == 0 ? wq : z == 1 ? wk : wv;
    const float* __restrict__ bias = z == 0 ? bq : z == 1 ? bk : bv;
    u16* __restrict__ outp = z == 0 ? Qb : z == 1 ? Kb : VTb;

    const int tid = threadIdx.x;
    const int m0 = blockIdx.y * 128;
    const int n0 = blockIdx.x * 128;
    const int wave = tid >> 6, lane = tid & 63;
    const int wm = (wave >> 1) * 64, wn = (wave & 1) * 64;
    const int g = lane >> 4, rw = lane & 15;

    f32x4 acc[4][4] = {};

    for (int kt = 0; kt < Kd; kt += 32) {
        __syncthreads();
#pragma unroll
        for (int j = 0; j < 2; ++j) {
            int c = wave * 128 + j * 64 + lane;
            int r = c >> 2, u = (c & 3) * 8;
            gl_lds16(&A [(size_t)(m0 + r) * Kd + kt + u], &As[c * 8]);
            gl_lds16(&Bw[(size_t)(n0 + r) * Kd + kt + u], &Bs[c * 8]);
        }
        __syncthreads();

        bf16x8 aF[4], bF[4];
#pragma unroll
        for (int mf = 0; mf < 4; ++mf)
            aF[mf] = *reinterpret_cast<const bf16x8*>(&As[(wm + mf * 16 + rw) * 32 + g * 8]);
#pragma unroll
        for (int nf = 0; nf < 4; ++nf)
            bF[nf] = *reinterpret_cast<const bf16x8*>(&Bs[(wn + nf * 16 + rw) * 32 + g * 8]);
#pragma unroll
        for (int mf = 0; mf < 4; ++mf)
#pragma unroll
            for (int nf = 0; nf < 4; ++nf)
                acc[mf][nf] = __builtin_amdgcn_mfma_f32_16x16x32_bf16(aF[mf], bF[nf], acc[mf][nf], 0, 0, 0);
    }

#pragma unroll
    for (int mf = 0; mf < 4; ++mf)
#pragma unroll
        for (int nf = 0; nf < 4; ++nf)
#pragma unroll
            for (int r = 0; r < 4; ++r) {
                int m = m0 + wm + mf * 16 + g * 4 + r;
                int n = n0 + wn + nf * 16 + rw;
                u16 hv = f2bf(acc[mf][nf][r] + bias[n]);
                int b = m >> 11, s = m & (GS - 1);
                int h = n >> 6, d = n & 63;
                if (z == 2)
                    outp[(((size_t)(b * GH + h)) * GD + d) * GS + s] = hv;
                else
                    outp[(((size_t)(b * GH + h)) * GS + s) * GD + d] = hv;
            }
}

__global__ __launch_bounds__(256)
void out_gemm(const u16* __restrict__ A, const u16* __restrict__ Bw,
              const float* __restrict__ bias, float* __restrict__ outp) {
    constexpr int Kd = GE, Nd = GE;
    __shared__ u16 As[128 * 32];
    __shared__ u16 Bs[128 * 32];

    const int tid = threadIdx.x;
    const int m0 = blockIdx.y * 128;
    const int n0 = blockIdx.x * 128;
    const int wave = tid >> 6, lane = tid & 63;
    const int wm = (wave >> 1) * 64, wn = (wave & 1) * 64;
    const int g = lane >> 4, rw = lane & 15;

    f32x4 acc[4][4] = {};

    for (int kt = 0; kt < Kd; kt += 32) {
        __syncthreads();
#pragma unroll
        for (int j = 0; j < 2; ++j) {
            int c = wave * 128 + j * 64 + lane;
            int r = c >> 2, u = (c & 3) * 8;
            gl_lds16(&A [(size_t)(m0 + r) * Kd + kt + u], &As[c * 8]);
            gl_lds16(&Bw[(size_t)(n0 + r) * Kd + kt + u], &Bs[c * 8]);
        }
        __syncthreads();

        bf16x8 aF[4], bF[4];
#pragma unroll
        for (int mf = 0; mf < 4; ++mf)
            aF[mf] = *reinterpret_cast<const bf16x8*>(&As[(wm + mf * 16 + rw) * 32 + g * 8]);
#pragma unroll
        for (int nf = 0; nf < 4; ++nf)
            bF[nf] = *reinterpret_cast<const bf16x8*>(&Bs[(wn + nf * 16 + rw) * 32 + g * 8]);
#pragma unroll
        for (int mf = 0; mf < 4; ++mf)
#pragma unroll
            for (int nf = 0; nf < 4; ++nf)
                acc[mf][nf] = __builtin_amdgcn_mfma_f32_16x16x32_bf16(aF[mf], bF[nf], acc[mf][nf], 0, 0, 0);
    }

#pragma unroll
    for (int mf = 0; mf < 4; ++mf)
#pragma unroll
        for (int nf = 0; nf < 4; ++nf)
#pragma unroll
            for (int r = 0; r < 4; ++r) {
                int m = m0 + wm + mf * 16 + g * 4 + r;
                int n = n0 + wn + nf * 16 + rw;
                outp[(size_t)m * Nd + n] = acc[mf][nf][r] + bias[n];
            }
}

// ---------------------------------------------------------------- attention
// R7: loop-invariant addresses hoisted. Per step only 2 pointer advances.
//   K src j=1 = j=0 + 8*GD;  V src j=1 = j=0 + 8*GS  ((r+8)&7 == r&7).
//   ds offsets: swz(l31+32,u) = swz(l31,u) + 2048 -> 4 offsets serve 16 reads.
template <int NSPLIT>
__global__ __launch_bounds__(256)
void attn_kernel(const u16* __restrict__ Q, const u16* __restrict__ Kp,
                 const u16* __restrict__ VT, u16* __restrict__ ctx,
                 float* __restrict__ Opart, float* __restrict__ Mpart,
                 float* __restrict__ Lpart) {
    int bh, qb, split;
    if (NSPLIT == 2) {
        const int wg = (blockIdx.x & 7) * 128 + (blockIdx.x >> 3);   // bijective, 1024%8==0
        bh = wg >> 5;
        split = wg & 1;
        qb = ((wg >> 1) & 15) * 128;
    } else {
        const int wg = (blockIdx.x & 7) * 64 + (blockIdx.x >> 3);
        bh = wg >> 4;
        split = 0;
        qb = (wg & 15) * 128;
    }
    const int wave = threadIdx.x >> 6;
    const int lane = threadIdx.x & 63;
    const int l31 = lane & 31;
    const int hi = lane >> 5;
    const int q0 = qb + wave * 32;
    constexpr int KVLEN = GS / NSPLIT;
    constexpr int NT2 = KVLEN / 64;          // even (16 or 8)
    const int kvbase = split * KVLEN;

    const u16* __restrict__ Qbh = Q  + (size_t)bh * GS * GD;
    const u16* __restrict__ Kbh = Kp + (size_t)bh * GS * GD;
    const u16* __restrict__ Vbh = VT + (size_t)bh * GD * GS;

    __shared__ u16 sK[2][4096];
    __shared__ u16 sV[2][4096];

    bf16x8 qf[4];
#pragma unroll
    for (int s = 0; s < 4; ++s)
        qf[s] = *reinterpret_cast<const bf16x8*>(
            Qbh + (size_t)(q0 + l31) * GD + hi * 8 + 16 * s);

    f32x16 O0 = {}, O1 = {};
    float m = -1e30f, lsum = 0.f;
    const float SC = 0.125f * 1.44269504088896f;   // D^-1/2 * log2(e)

    // ---- hoisted staging addresses (chunk c0 = wave*128 + lane)
    const int c0 = wave * 128 + lane;
    const int r0 = c0 >> 3, w0 = c0 & 7;
    const int swzcol = (w0 ^ (r0 & 7)) * 8;
    const u16* kSrc = Kbh + (size_t)(kvbase + r0) * GD + swzcol;   // += 64*GD per step
    const u16* vSrc = Vbh + (size_t)r0 * GS + kvbase + swzcol;     // += 64 per step
    u16* const dK0 = &sK[0][c0 * 8];
    u16* const dK1 = &sK[1][c0 * 8];
    u16* const dV0 = &sV[0][c0 * 8];
    u16* const dV1 = &sV[1][c0 * 8];

    auto stageTo = [&](u16* dk, u16* dv, const u16* ks, const u16* vs) {
        gl_lds16(ks,            dk);
        gl_lds16(ks + 8 * GD,   dk + 512);     // chunk c0+64: r+8, same swizzle col
        gl_lds16(vs,            dv);
        gl_lds16(vs + 8 * GS,   dv + 512);
    };

    // ---- hoisted ds_read offsets (u16 units); +2048 gives the l31+32 row
    int offA[4];
#pragma unroll
    for (int s = 0; s < 4; ++s)
        offA[s] = l31 * 64 + (((2 * s + hi) ^ (l31 & 7)) * 8);

    // ---- one fused step: compute from (bK,bV), prefetch handled by caller
    auto step = [&](const u16* bK, const u16* bV) {
        f32x16 sa = {}, sb = {};
        bf16x8 ka[4], kb[4];
#pragma unroll
        for (int s = 0; s < 4; ++s) {
            ka[s] = *reinterpret_cast<const bf16x8*>(&bK[offA[s]]);
            kb[s] = *reinterpret_cast<const bf16x8*>(&bK[offA[s] + 2048]);
        }
        __builtin_amdgcn_s_setprio(1);
#pragma unroll
        for (int s = 0; s < 4; ++s) {
            sa = __builtin_amdgcn_mfma_f32_32x32x16_bf16(ka[s], qf[s], sa, 0, 0, 0);
            sb = __builtin_amdgcn_mfma_f32_32x32x16_bf16(kb[s], qf[s], sb, 0, 0, 0);
        }
        __builtin_amdgcn_s_setprio(0);

        bf16x8 vf0[4], vf1[4];
#pragma unroll
        for (int s = 0; s < 4; ++s) {
            vf0[s] = *reinterpret_cast<const bf16x8*>(&bV[offA[s]]);
            vf1[s] = *reinterpret_cast<const bf16x8*>(&bV[offA[s] + 2048]);
        }

        // ---- online softmax
        float t16[16];
#pragma unroll
        for (int r = 0; r < 16; ++r) t16[r] = fmaxf(sa[r], sb[r]);
        float u0 = fmaxf(fmaxf(t16[0],  t16[1]),  t16[2]);
        float u1 = fmaxf(fmaxf(t16[3],  t16[4]),  t16[5]);
        float u2 = fmaxf(fmaxf(t16[6],  t16[7]),  t16[8]);
        float u3 = fmaxf(fmaxf(t16[9],  t16[10]), t16[11]);
        float u4 = fmaxf(fmaxf(t16[12], t16[13]), t16[14]);
        float w0_ = fmaxf(fmaxf(u0, u1), u2);
        float w1_ = fmaxf(fmaxf(u3, u4), t16[15]);
        float mx = fmaxf(w0_, w1_);
        mx = fmaxf(mx, xchg32(mx));
        float mxs = mx * SC;
        if (__any(mxs > m + 8.f)) {       // T13 defer-max
            float mn = fmaxf(m, mxs);
            float alpha = __builtin_amdgcn_exp2f(m - mn);
            m = mn;
            lsum *= alpha;
#pragma unroll
            for (int r = 0; r < 16; ++r) { O0[r] *= alpha; O1[r] *= alpha; }
        }
        float pa[16], pb[16];
#pragma unroll
        for (int r = 0; r < 16; ++r) {
            pa[r] = __builtin_amdgcn_exp2f(fmaf(sa[r], SC, -m));
            pb[r] = __builtin_amdgcn_exp2f(fmaf(sb[r], SC, -m));
        }
        float s16[16];
#pragma unroll
        for (int r = 0; r < 16; ++r) s16[r] = pa[r] + pb[r];
#pragma unroll
        for (int r = 0; r < 8; ++r) s16[r] += s16[r + 8];
#pragma unroll
        for (int r = 0; r < 4; ++r) s16[r] += s16[r + 4];
        lsum += (s16[0] + s16[1]) + (s16[2] + s16[3]);   // own-half; xchg deferred

        // ---- pack P -> PV B-fragments
        u32 wa[8], wb[8];
#pragma unroll
        for (int i = 0; i < 8; ++i) {
            wa[i] = cvtpk(pa[2 * i], pa[2 * i + 1]);
            wb[i] = cvtpk(pb[2 * i], pb[2 * i + 1]);
        }
        plswap(wa[0], wa[2]); plswap(wa[1], wa[3]);
        plswap(wa[4], wa[6]); plswap(wa[5], wa[7]);
        plswap(wb[0], wb[2]); plswap(wb[1], wb[3]);
        plswap(wb[4], wb[6]); plswap(wb[5], wb[7]);
        u32x4 a0 = {wa[0], wa[1], wa[2], wa[3]};
        u32x4 a1 = {wa[4], wa[5], wa[6], wa[7]};
        u32x4 b0 = {wb[0], wb[1], wb[2], wb[3]};
        u32x4 b1 = {wb[4], wb[5], wb[6], wb[7]};
        bf16x8 pva0 = __builtin_bit_cast(bf16x8, a0);
        bf16x8 pva1 = __builtin_bit_cast(bf16x8, a1);
        bf16x8 pvb0 = __builtin_bit_cast(bf16x8, b0);
        bf16x8 pvb1 = __builtin_bit_cast(bf16x8, b1);

        __builtin_amdgcn_s_setprio(1);
        O0 = __builtin_amdgcn_mfma_f32_32x32x16_bf16(vf0[0], pva0, O0, 0, 0, 0);
        O0 = __builtin_amdgcn_mfma_f32_32x32x16_bf16(vf0[1], pva1, O0, 0, 0, 0);
        O0 = __builtin_amdgcn_mfma_f32_32x32x16_bf16(vf0[2], pvb0, O0, 0, 0, 0);
        O0 = __builtin_amdgcn_mfma_f32_32x32x16_bf16(vf0[3], pvb1, O0, 0, 0, 0);
        O1 = __builtin_amdgcn_mfma_f32_32x32x16_bf16(vf1[0], pva0, O1, 0, 0, 0);
        O1 = __builtin_amdgcn_mfma_f32_32x32x16_bf16(vf1[1], pva1, O1, 0, 0, 0);
        O1 = __builtin_amdgcn_mfma_f32_32x32x16_bf16(vf1[2], pvb0, O1, 0, 0, 0);
        O1 = __builtin_amdgcn_mfma_f32_32x32x16_bf16(vf1[3], pvb1, O1, 0, 0, 0);
        __builtin_amdgcn_s_setprio(0);
        __syncthreads();
    };

    stageTo(dK0, dV0, kSrc, vSrc);
    kSrc += 64 * GD; vSrc += 64;
    __syncthreads();

#pragma unroll 1
    for (int t = 0; t < NT2; t += 2) {
        // buf0 compute, prefetch t+1 into buf1
        stageTo(dK1, dV1, kSrc, vSrc);
        kSrc += 64 * GD; vSrc += 64;
        step(sK[0], sV[0]);
        // buf1 compute, prefetch t+2 into buf0
        if (t + 2 < NT2) {
            stageTo(dK0, dV0, kSrc, vSrc);
            kSrc += 64 * GD; vSrc += 64;
        }
        step(sK[1], sV[1]);
    }

    lsum += xchg32(lsum);      // deferred cross-half combine (alphas identical)

    if (NSPLIT == 2) {
        const int wt = bh * 64 + (q0 >> 5);
        const size_t base = ((size_t)wt * 2 + split) * PSTRIDE;
#pragma unroll
        for (int r = 0; r < 16; ++r) {
            int d = (r & 3) + 8 * (r >> 2) + 4 * hi;
            Opart[base + (size_t)d * 32 + l31]        = O0[r];
            Opart[base + (size_t)(d + 32) * 32 + l31] = O1[r];
        }
        if (hi == 0) {
            Mpart[(wt * 2 + split) * 32 + l31] = m;
            Lpart[(wt * 2 + split) * 32 + l31] = lsum;
        }
    } else {
        const int bb = bh >> 4, h = bh & 15;
        const float inv = 1.0f / lsum;
        u16* crow = ctx + ((size_t)(bb * GS + q0 + l31)) * GE + h * 64;
#pragma unroll
        for (int g2 = 0; g2 < 4; ++g2) {
            ushort4 st0, st1;
            st0.x = f2bf(O0[4 * g2 + 0] * inv); st0.y = f2bf(O0[4 * g2 + 1] * inv);
            st0.z = f2bf(O0[4 * g2 + 2] * inv); st0.w = f2bf(O0[4 * g2 + 3] * inv);
            st1.x = f2bf(O1[4 * g2 + 0] * inv); st1.y = f2bf(O1[4 * g2 + 1] * inv);
            st1.z = f2bf(O1[4 * g2 + 2] * inv); st1.w = f2bf(O1[4 * g2 + 3] * inv);
            *reinterpret_cast<ushort4*>(crow + 8 * g2 + 4 * hi)      = st0;
            *reinterpret_cast<ushort4*>(crow + 32 + 8 * g2 + 4 * hi) = st1;
        }
    }
}

// ---------------------------------------------------------------- combine
__global__ __launch_bounds__(256)
void combine_kernel(const float* __restrict__ Opart, const float* __restrict__ Mpart,
                    const float* __restrict__ Lpart, u16* __restrict__ ctx) {
    const int wt = blockIdx.x;
    const int bh = wt >> 6, bb = bh >> 4, h = bh & 15;
    const int q0 = (wt & 63) * 32;
    const int q = threadIdx.x & 31, db = threadIdx.x >> 5;
    const size_t b0 = (size_t)wt * 2 * PSTRIDE, b1 = b0 + PSTRIDE;

    float m0 = Mpart[(wt * 2 + 0) * 32 + q], m1 = Mpart[(wt * 2 + 1) * 32 + q];
    float l0 = Lpart[(wt * 2 + 0) * 32 + q], l1 = Lpart[(wt * 2 + 1) * 32 + q];
    float M = fmaxf(m0, m1);
    float c0 = exp2f(m0 - M), c1 = exp2f(m1 - M);
    float inv = 1.f / (c0 * l0 + c1 * l1);
    c0 *= inv; c1 *= inv;

    u16* crow = ctx + ((size_t)(bb * GS + q0 + q)) * GE + h * 64 + db * 8;
    ushort4 s0, s1;
    float o[8];
#pragma unroll
    for (int i = 0; i < 8; ++i) {
        int d = db * 8 + i;
        o[i] = c0 * Opart[b0 + (size_t)d * 32 + q] + c1 * Opart[b1 + (size_t)d * 32 + q];
    }
    s0.x = f2bf(o[0]); s0.y = f2bf(o[1]); s0.z = f2bf(o[2]); s0.w = f2bf(o[3]);
    s1.x = f2bf(o[4]); s1.y = f2bf(o[5]); s1.z = f2bf(o[6]); s1.w = f2bf(o[7]);
    *reinterpret_cast<ushort4*>(crow)     = s0;
    *reinterpret_cast<ushort4*>(crow + 4) = s1;
}

// ---------------------------------------------------------------- launcher
extern "C" void kernel_launch(void* const* d_in, const int* in_sizes, int n_in,
                              void* d_out, int out_size, void* d_ws, size_t ws_size,
                              hipStream_t stream) {
    (void)in_sizes; (void)n_in; (void)out_size;

    const float* x  = (const float*)d_in[0];
    const float* Wq = (const float*)d_in[1];
    const float* bq = (const float*)d_in[2];
    const float* Wk = (const float*)d_in[3];
    const float* bk = (const float*)d_in[4];
    const float* Wv = (const float*)d_in[5];
    const float* bv = (const float*)d_in[6];
    const float* Wo = (const float*)d_in[7];
    const float* bo = (const float*)d_in[8];
    float* out = (float*)d_out;

    char* ws = (char*)d_ws;
    u16* xb  = (u16*)(ws);                    // 8 MB  [4096,1024]
    u16* wqb = (u16*)(ws + (8ll  << 20));
    u16* wkb = (u16*)(ws + (10ll << 20));
    u16* wvb = (u16*)(ws + (12ll << 20));
    u16* wob = (u16*)(ws + (14ll << 20));
    u16* Qb  = (u16*)(ws + (16ll << 20));     // [B,H,S,D]
    u16* Kb  = (u16*)(ws + (24ll << 20));     // [B,H,S,D]
    u16* VTb = (u16*)(ws + (32ll << 20));     // [B,H,D,S]
    u16* ctx = (u16*)(ws + (40ll << 20));     // [B,S,E]
    float* Opart = (float*)(ws + (48ll << 20));   // 32 MB
    float* Mpart = (float*)(ws + (80ll << 20));
    float* Lpart = (float*)(ws + (80ll << 20) + (512ll << 10));
    const bool split2 = ws_size >= (81ll << 20);

    cvt_kernel<<<2048, 256, 0, stream>>>(x, xb, GM * GE);
    cvtw_kernel<<<dim3(512, 4), 256, 0, stream>>>(Wq, Wk, Wv, Wo, wqb, wkb, wvb, wob);

    qkv_gemm<<<dim3(GE / 128, GM / 128, 3), 256, 0, stream>>>(
        xb, wqb, wkb, wvb, bq, bk, bv, Qb, Kb, VTb);

    if (split2) {
        attn_kernel<2><<<dim3(1024), 256, 0, stream>>>(Qb, Kb, VTb, ctx, Opart, Mpart, Lpart);
        combine_kernel<<<dim3(2048), 256, 0, stream>>>(Opart, Mpart, Lpart, ctx);
    } else {
        attn_kernel<1><<<dim3(512), 256, 0, stream>>>(Qb, Kb, VTb, ctx, Opart, Mpart, Lpart);
    }

    out_gemm<<<dim3(GE / 128, GM / 128), 256, 0, stream>>>(ctx, wob, bo, out);
}